// Round 4
// baseline (1764.148 us; speedup 1.0000x reference)
//
#include <hip/hip_runtime.h>
#include <cstdint>
#include <cstddef>

using short8  = __attribute__((ext_vector_type(8))) short;
using floatx4 = __attribute__((ext_vector_type(4))) float;
typedef unsigned short u16;

constexpr int NN = 30000;   // nodes
constexpr int NE = 60000;   // edges / messages
constexpr int BATCH = 256;
constexpr int VV = 40;
constexpr int NBOND = 4;
constexpr int TT = 6;
constexpr int PT = 1536, PA = 1280, PB = 2560;

__device__ __forceinline__ float b2f(u16 h) {
  union { unsigned u; float f; } v; v.u = ((unsigned)h) << 16; return v.f;
}
__device__ __forceinline__ u16 f2b(float f) {
  union { float f; unsigned u; } v; v.f = f;
  unsigned r = v.u + 0x7FFFu + ((v.u >> 16) & 1u);
  return (u16)(r >> 16);
}
__device__ __forceinline__ float lo16(unsigned u) {
  union { unsigned x; float f; } v; v.x = u << 16; return v.f;
}
__device__ __forceinline__ float hi16(unsigned u) {
  union { unsigned x; float f; } v; v.x = u & 0xffff0000u; return v.f;
}
__device__ __forceinline__ unsigned pack2(float a, float b) {
  return ((unsigned)f2b(a)) | (((unsigned)f2b(b)) << 16);
}

// ---------------------------------------------------------------------------
// bf16 MFMA GEMM: C[M,256] = epi(A[M,K] @ B[K,256])
// MODE 0: C = acc
// MODE 1: C = relu(acc + bias[col])
// MODE 2: e = row % modrows; C = (e==0) ? 0 : relu(acc + aux[e,col] + bias[col])
// MODE 3: e = row % modrows; C = vm[row] ? relu(acc + aux[e,col] + bias[col]) : 0
// A row-major (bf16, or f32 when AF32), Bt = B^T row-major bf16 [256,K].
// ---------------------------------------------------------------------------
template<int MODE, int AF32>
__global__ __launch_bounds__(256) void gemm_bt_kernel(
    const void* __restrict__ Av, int lda, int M,
    const u16* __restrict__ Bt, int K,
    u16* __restrict__ C, int ldc, const float* __restrict__ bias,
    const u16* __restrict__ aux, const int* __restrict__ vm, int modrows)
{
  __shared__ __align__(16) u16 As[128][56];
  __shared__ __align__(16) u16 Bs[128][56];
  const int tid  = threadIdx.x;
  const int wave = tid >> 6, lane = tid & 63;
  const int wm = wave >> 1, wn = wave & 1;
  const int lr = lane & 15, lk = (lane >> 4) * 8;
  const int rowbase = blockIdx.x * 128;
  const int colbase = blockIdx.y * 128;

  floatx4 acc[4][4];
#pragma unroll
  for (int i = 0; i < 4; i++)
#pragma unroll
    for (int j = 0; j < 4; j++) acc[i][j] = {0.f, 0.f, 0.f, 0.f};

  for (int k0 = 0; k0 < K; k0 += 32) {
#pragma unroll
    for (int r = 0; r < 2; r++) {
      int c = tid + 256 * r;
      int row = c >> 2, cc = (c & 3) * 8;
      int grow = rowbase + row;
      uint4 av = {0u, 0u, 0u, 0u};
      if (AF32) {
        if (grow < M) {
          const float* Af = (const float*)Av;
          float4 f0 = *(const float4*)(Af + (long)grow * lda + k0 + cc);
          float4 f1 = *(const float4*)(Af + (long)grow * lda + k0 + cc + 4);
          av.x = pack2(f0.x, f0.y); av.y = pack2(f0.z, f0.w);
          av.z = pack2(f1.x, f1.y); av.w = pack2(f1.z, f1.w);
        }
      } else {
        if (grow < M) av = *(const uint4*)((const u16*)Av + (long)grow * lda + k0 + cc);
      }
      *(uint4*)(&As[row][cc]) = av;
      uint4 bv = *(const uint4*)(Bt + (long)(colbase + row) * K + k0 + cc);
      *(uint4*)(&Bs[row][cc]) = bv;
    }
    __syncthreads();
    short8 af[4], bf[4];
#pragma unroll
    for (int mt = 0; mt < 4; mt++) af[mt] = *(const short8*)(&As[wm * 64 + mt * 16 + lr][lk]);
#pragma unroll
    for (int nt = 0; nt < 4; nt++) bf[nt] = *(const short8*)(&Bs[wn * 64 + nt * 16 + lr][lk]);
#pragma unroll
    for (int mt = 0; mt < 4; mt++)
#pragma unroll
      for (int nt = 0; nt < 4; nt++)
        acc[mt][nt] = __builtin_amdgcn_mfma_f32_16x16x32_bf16(af[mt], bf[nt], acc[mt][nt], 0, 0, 0);
    __syncthreads();
  }

  const int rq = (lane >> 4) * 4;
#pragma unroll
  for (int mt = 0; mt < 4; mt++) {
#pragma unroll
    for (int nt = 0; nt < 4; nt++) {
      int gcol = colbase + wn * 64 + nt * 16 + lr;
#pragma unroll
      for (int r2 = 0; r2 < 4; r2++) {
        int grow = rowbase + wm * 64 + mt * 16 + rq + r2;
        if (grow < M) {
          float v = acc[mt][nt][r2];
          if (MODE == 1) { v += bias[gcol]; v = v > 0.f ? v : 0.f; }
          if (MODE == 2) {
            int e = grow % modrows;
            v += b2f(aux[(long)e * 256 + gcol]) + bias[gcol];
            v = v > 0.f ? v : 0.f;
            if (e == 0) v = 0.f;
          }
          if (MODE == 3) {
            int e = grow % modrows;
            v += b2f(aux[(long)e * 256 + gcol]) + bias[gcol];
            v = v > 0.f ? v : 0.f;
            if (vm[grow] == 0) v = 0.f;
          }
          C[(long)grow * ldc + gcol] = f2b(v);
        }
      }
    }
  }
}

// ---------------------------------------------------------------------------
// Merged topo+atom head GEMM: A = tva [(PT+PA) x 544]; blocks with
// rowbase < PT use (Bt1,b1) else (Bt2,b2). relu+bias. K=544, N=256.
// ---------------------------------------------------------------------------
__global__ __launch_bounds__(256) void gemm_ta_kernel(
    const u16* __restrict__ A,
    const u16* __restrict__ Bt1, const u16* __restrict__ Bt2,
    const float* __restrict__ b1, const float* __restrict__ b2,
    u16* __restrict__ C)
{
  constexpr int K = 544;
  __shared__ __align__(16) u16 As[128][56];
  __shared__ __align__(16) u16 Bs[128][56];
  const int tid  = threadIdx.x;
  const int wave = tid >> 6, lane = tid & 63;
  const int wm = wave >> 1, wn = wave & 1;
  const int lr = lane & 15, lk = (lane >> 4) * 8;
  const int rowbase = blockIdx.x * 128;
  const int colbase = blockIdx.y * 128;
  const u16* Bt = (rowbase < PT) ? Bt1 : Bt2;
  const float* bias = (rowbase < PT) ? b1 : b2;

  floatx4 acc[4][4];
#pragma unroll
  for (int i = 0; i < 4; i++)
#pragma unroll
    for (int j = 0; j < 4; j++) acc[i][j] = {0.f, 0.f, 0.f, 0.f};

  for (int k0 = 0; k0 < K; k0 += 32) {
#pragma unroll
    for (int r = 0; r < 2; r++) {
      int c = tid + 256 * r;
      int row = c >> 2, cc = (c & 3) * 8;
      int grow = rowbase + row;
      uint4 av = *(const uint4*)(A + (long)grow * K + k0 + cc);
      *(uint4*)(&As[row][cc]) = av;
      uint4 bv = *(const uint4*)(Bt + (long)(colbase + row) * K + k0 + cc);
      *(uint4*)(&Bs[row][cc]) = bv;
    }
    __syncthreads();
    short8 af[4], bf[4];
#pragma unroll
    for (int mt = 0; mt < 4; mt++) af[mt] = *(const short8*)(&As[wm * 64 + mt * 16 + lr][lk]);
#pragma unroll
    for (int nt = 0; nt < 4; nt++) bf[nt] = *(const short8*)(&Bs[wn * 64 + nt * 16 + lr][lk]);
#pragma unroll
    for (int mt = 0; mt < 4; mt++)
#pragma unroll
      for (int nt = 0; nt < 4; nt++)
        acc[mt][nt] = __builtin_amdgcn_mfma_f32_16x16x32_bf16(af[mt], bf[nt], acc[mt][nt], 0, 0, 0);
    __syncthreads();
  }

  const int rq = (lane >> 4) * 4;
#pragma unroll
  for (int mt = 0; mt < 4; mt++) {
#pragma unroll
    for (int nt = 0; nt < 4; nt++) {
      int gcol = colbase + wn * 64 + nt * 16 + lr;
#pragma unroll
      for (int r2 = 0; r2 < 4; r2++) {
        int grow = rowbase + wm * 64 + mt * 16 + rq + r2;
        float v = acc[mt][nt][r2] + bias[gcol];
        v = v > 0.f ? v : 0.f;
        C[(long)grow * 256 + gcol] = f2b(v);
      }
    }
  }
}

// ---------------------------------------------------------------------------
// gathers: 8 rows/block, 32 threads/row, 16B/thread. emask folded in.
// H1=1: tab = preB (step-invariant), contribution = (idx>0)? relu(pre[idx]+b) : 0
// H1=0: tab = T1 chunk (rows tl*NE + idx, row 0 of each step is zero), plain sum
// ---------------------------------------------------------------------------
template<int H1>
__global__ __launch_bounds__(256) void gather_e_kernel(
    const u16* __restrict__ tab, const int* __restrict__ graph,
    const int* __restrict__ em, const float* __restrict__ bias,
    int t0, u16* __restrict__ G)
{
  int r0 = blockIdx.x * 8;
  int tl = r0 / NE;
  int e0 = r0 - tl * NE;
  int t = t0 + tl;
  __shared__ int sidx[8][6];
  int tid = threadIdx.x;
  if (tid < 48) {
    int rr = tid / 6, j = tid - rr * 6;
    int v = graph[(long)(e0 + rr) * 6 + j];
    v *= em[(long)t * NE + v];
    sidx[rr][j] = H1 ? v : (tl * NE + v);
  }
  __syncthreads();
  int rl = tid >> 5, ch = (tid & 31) * 8;
  float a0 = 0.f, a1 = 0.f, a2 = 0.f, a3 = 0.f, a4 = 0.f, a5 = 0.f, a6 = 0.f, a7 = 0.f;
  float4 b0, b1;
  if (H1) { b0 = *(const float4*)(bias + ch); b1 = *(const float4*)(bias + ch + 4); }
#pragma unroll
  for (int j = 0; j < 6; j++) {
    int ix = sidx[rl][j];
    uint4 g = *(const uint4*)(tab + (long)ix * 256 + ch);
    if (H1) {
      if (ix > 0) {
        a0 += fmaxf(lo16(g.x) + b0.x, 0.f); a1 += fmaxf(hi16(g.x) + b0.y, 0.f);
        a2 += fmaxf(lo16(g.y) + b0.z, 0.f); a3 += fmaxf(hi16(g.y) + b0.w, 0.f);
        a4 += fmaxf(lo16(g.z) + b1.x, 0.f); a5 += fmaxf(hi16(g.z) + b1.y, 0.f);
        a6 += fmaxf(lo16(g.w) + b1.z, 0.f); a7 += fmaxf(hi16(g.w) + b1.w, 0.f);
      }
    } else {
      a0 += lo16(g.x); a1 += hi16(g.x); a2 += lo16(g.y); a3 += hi16(g.y);
      a4 += lo16(g.z); a5 += hi16(g.z); a6 += lo16(g.w); a7 += hi16(g.w);
    }
  }
  uint4 o; o.x = pack2(a0, a1); o.y = pack2(a2, a3); o.z = pack2(a4, a5); o.w = pack2(a6, a7);
  *(uint4*)(G + (long)(r0 + rl) * 256 + ch) = o;
}

// node-side gather: Gn[tl*NN+n] = sum_j T1[tl*NE + ag(n,j)]
__global__ __launch_bounds__(256) void gather_n_kernel(
    const u16* __restrict__ tab, const int* __restrict__ graph,
    const int* __restrict__ em, int t0, u16* __restrict__ Gn)
{
  int r0 = blockIdx.x * 8;
  int tl = r0 / NN;
  int n0 = r0 - tl * NN;
  int t = t0 + tl;
  __shared__ int sidx[8][6];
  int tid = threadIdx.x;
  if (tid < 48) {
    int rr = tid / 6, j = tid - rr * 6;
    int v = graph[(long)(n0 + rr) * 6 + j];
    v *= em[(long)t * NE + v];
    sidx[rr][j] = tl * NE + v;
  }
  __syncthreads();
  int rl = tid >> 5, ch = (tid & 31) * 8;
  float a0 = 0.f, a1 = 0.f, a2 = 0.f, a3 = 0.f, a4 = 0.f, a5 = 0.f, a6 = 0.f, a7 = 0.f;
#pragma unroll
  for (int j = 0; j < 6; j++) {
    uint4 g = *(const uint4*)(tab + (long)sidx[rl][j] * 256 + ch);
    a0 += lo16(g.x); a1 += hi16(g.x); a2 += lo16(g.y); a3 += hi16(g.y);
    a4 += lo16(g.z); a5 += hi16(g.z); a6 += lo16(g.w); a7 += hi16(g.w);
  }
  uint4 o; o.x = pack2(a0, a1); o.y = pack2(a2, a3); o.z = pack2(a4, a5); o.w = pack2(a6, a7);
  *(uint4*)(Gn + (long)(r0 + rl) * 256 + ch) = o;
}

// zero gvec + out
__global__ __launch_bounds__(256) void init_zero_kernel(float* __restrict__ gv,
                                                        float* __restrict__ out)
{
  int i = blockIdx.x * 256 + threadIdx.x;
  gv[i] = 0.f;
  if (i == 0) out[0] = 0.f;
}

// all 9 weight transposes in one dispatch. Bt[n][k]=bf16(W[k][n]), k>=K -> 0.
__global__ __launch_bounds__(256) void transpose_all_kernel(
    const float* W_h, const float* U_h, const float* W_o,
    const float* tw1, const float* aw1, const float* bw1,
    const float* rw, const float* ww,
    u16* Wh_t, u16* Uh_t, u16* Wo1_t, u16* Wo2_t,
    u16* tw1_t, u16* aw1_t, u16* bw1_t, u16* rw_t, u16* ww_t)
{
  int b = blockIdx.x;
  const float* W; int K, Kpad; u16* Bt; int base;
  if      (b < 256)  { W = W_h;  K = 256; Kpad = 256; Bt = Wh_t;  base = 0; }
  else if (b < 512)  { W = U_h;  K = 256; Kpad = 256; Bt = Uh_t;  base = 256; }
  else if (b < 768)  { W = W_o;  K = 256; Kpad = 256; Bt = Wo1_t; base = 512; }
  else if (b < 1024) { W = W_o + 256 * 256; K = 256; Kpad = 256; Bt = Wo2_t; base = 768; }
  else if (b < 1568) { W = tw1;  K = 544; Kpad = 544; Bt = tw1_t; base = 1024; }
  else if (b < 2112) { W = aw1;  K = 544; Kpad = 544; Bt = aw1_t; base = 1568; }
  else if (b < 2912) { W = bw1;  K = 800; Kpad = 800; Bt = bw1_t; base = 2112; }
  else if (b < 3232) { W = rw;   K = 296; Kpad = 320; Bt = rw_t;  base = 2912; }
  else               { W = ww;   K = 260; Kpad = 288; Bt = ww_t;  base = 3232; }
  int idx = (b - base) * 256 + threadIdx.x;
  int n = idx / Kpad, k = idx - n * Kpad;
  Bt[idx] = (k < K) ? f2b(W[(long)k * 256 + n]) : (u16)0;
}

// segmented-sum graph vectors: 32 rows/block, atomic flush on segment change.
__global__ __launch_bounds__(256) void gvec_atomic_kernel(const u16* __restrict__ node,
                                                          const int* __restrict__ n2g,
                                                          float* __restrict__ gv, int t0)
{
  int tl = blockIdx.y;
  int r0 = blockIdx.x * 32;
  int h = threadIdx.x;
  const u16* nd = node + (long)tl * NN * 256;
  float* gb = gv + (long)(t0 + tl) * BATCH * 256;
  int rend = r0 + 32; if (rend > NN) rend = NN;
  int gprev = n2g[r0];
  float acc = 0.f;
  for (int r = r0; r < rend; r++) {
    int g = n2g[r];
    if (g != gprev) { atomicAdd(gb + gprev * 256 + h, acc); acc = 0.f; gprev = g; }
    acc += b2f(nd[(long)r * 256 + h]);
  }
  atomicAdd(gb + gprev * 256 + h, acc);
}

// scatter node rows with step in [t0, t0+TB) into head-input matrices
__global__ __launch_bounds__(256) void head_gather_kernel(int t0, int TB,
    const u16* __restrict__ node,
    const int* __restrict__ tstep, const int* __restrict__ txid,
    const int* __restrict__ astep, const int* __restrict__ axid,
    const int* __restrict__ bstep, const int* __restrict__ bzid,
    u16* __restrict__ tv, u16* __restrict__ av, u16* __restrict__ bv,
    u16* __restrict__ wbin)
{
  int wave = threadIdx.x >> 6, lane = threadIdx.x & 63;
  int r = blockIdx.x * 4 + wave;
  int c = lane * 4;
  if (r < PT) {
    int st = tstep[r];
    if (st < t0 || st >= t0 + TB) return;
    ushort4 v = *(const ushort4*)(node + ((long)(st - t0) * NN + txid[r]) * 256 + c);
    *(ushort4*)(tv + (long)r * 544 + 256 + c) = v;
  } else if (r < PT + PA) {
    int i = r - PT;
    int st = astep[i];
    if (st < t0 || st >= t0 + TB) return;
    ushort4 v = *(const ushort4*)(node + ((long)(st - t0) * NN + axid[i]) * 256 + c);
    *(ushort4*)(av + (long)i * 544 + 256 + c) = v;
  } else if (r < PT + PA + PB) {
    int i = r - PT - PA;
    int st = bstep[i];
    if (st < t0 || st >= t0 + TB) return;
    ushort4 v = *(const ushort4*)(node + ((long)(st - t0) * NN + bzid[i]) * 256 + c);
    *(ushort4*)(bv + (long)i * 800 + 512 + c) = v;
    *(ushort4*)(wbin + (long)i * 288 + c) = v;
  }
}

// fill gvec / src / one-hot segments of head inputs (after all steps)
__global__ __launch_bounds__(256) void build_static_kernel(
    const float* __restrict__ gvec, const float* __restrict__ src,
    const int* __restrict__ tstep, const int* __restrict__ tbid,
    const int* __restrict__ astep, const int* __restrict__ abid,
    const int* __restrict__ bstep, const int* __restrict__ bbid,
    const int* __restrict__ blabel, const int* __restrict__ batype,
    u16* __restrict__ tv, u16* __restrict__ av, u16* __restrict__ bv,
    u16* __restrict__ wbin, u16* __restrict__ rbin)
{
  int wave = threadIdx.x >> 6, lane = threadIdx.x & 63;
  int r = blockIdx.x * 4 + wave;
  int c = lane * 4;
  if (r < PT) {
    int st = tstep[r], bid = tbid[r];
    const float* g = gvec + ((long)st * BATCH + bid) * 256;
    u16* d = tv + (long)r * 544;
    float4 g4 = *(const float4*)(g + c);
    d[c] = f2b(g4.x); d[c + 1] = f2b(g4.y); d[c + 2] = f2b(g4.z); d[c + 3] = f2b(g4.w);
    if (lane < 8) {
      float4 s4 = *(const float4*)(src + bid * 32 + c);
      d[512 + c] = f2b(s4.x); d[512 + c + 1] = f2b(s4.y);
      d[512 + c + 2] = f2b(s4.z); d[512 + c + 3] = f2b(s4.w);
    }
  } else if (r < PT + PA) {
    int i = r - PT;
    int st = astep[i], bid = abid[i];
    const float* g = gvec + ((long)st * BATCH + bid) * 256;
    u16* d = av + (long)i * 544;
    float4 g4 = *(const float4*)(g + c);
    d[c] = f2b(g4.x); d[c + 1] = f2b(g4.y); d[c + 2] = f2b(g4.z); d[c + 3] = f2b(g4.w);
    if (lane < 8) {
      float4 s4 = *(const float4*)(src + bid * 32 + c);
      d[512 + c] = f2b(s4.x); d[512 + c + 1] = f2b(s4.y);
      d[512 + c + 2] = f2b(s4.z); d[512 + c + 3] = f2b(s4.w);
    }
  } else if (r < PT + PA + PB) {
    int i = r - PT - PA;
    int st = bstep[i], bid = bbid[i];
    const float* g = gvec + ((long)st * BATCH + bid) * 256;
    u16* d = bv + (long)i * 800;
    float4 g4 = *(const float4*)(g + c);
    d[c] = f2b(g4.x); d[c + 1] = f2b(g4.y); d[c + 2] = f2b(g4.z); d[c + 3] = f2b(g4.w);
    if (lane < 8) {
      float4 s4 = *(const float4*)(src + bid * 32 + c);
      d[768 + c] = f2b(s4.x); d[768 + c + 1] = f2b(s4.y);
      d[768 + c + 2] = f2b(s4.z); d[768 + c + 3] = f2b(s4.w);
      int bl = blabel[i];
      u16* wd = wbin + (long)i * 288 + 256;
      for (int q = 0; q < 4; q++) {
        int k = c + q;
        wd[k] = f2b((k < NBOND && bl == k) ? 1.f : 0.f);
      }
    }
    if (lane < 16) {
      int at = batype[i];
      u16* rd = rbin + (long)i * 320 + 256;
      for (int q = 0; q < 4; q++) {
        int k = c + q;
        rd[k] = f2b((k < VV && at == k) ? 1.f : 0.f);
      }
    }
  }
}

// rbin[r][0:256] = sum_{j in [gs[r], r)} wb[j] * (blabel[j] > 0)
__global__ __launch_bounds__(256) void hist_kernel(
    const u16* __restrict__ wb, const int* __restrict__ gs_arr,
    const int* __restrict__ blabel, u16* __restrict__ rbin)
{
  int wave = threadIdx.x >> 6, lane = threadIdx.x & 63;
  int r = blockIdx.x * 4 + wave;
  if (r >= PB) return;
  int c = lane * 4;
  float a0 = 0.f, a1 = 0.f, a2 = 0.f, a3 = 0.f;
  int gs = gs_arr[r];
  for (int j = gs; j < r; j++) {
    if (blabel[j] > 0) {
      ushort4 g = *(const ushort4*)(wb + (long)j * 256 + c);
      a0 += b2f(g.x); a1 += b2f(g.y); a2 += b2f(g.z); a3 += b2f(g.w);
    }
  }
  u16* rd = rbin + (long)r * 320;
  rd[c] = f2b(a0); rd[c + 1] = f2b(a1); rd[c + 2] = f2b(a2); rd[c + 3] = f2b(a3);
}

// all three losses in one dispatch:
// blocks [0,384): topo BCE; [384,704): atom CE (NC=40); [704,1344): bond CE (NC=4)
__global__ __launch_bounds__(256) void loss_all_kernel(
    const u16* __restrict__ t_hid, const float* __restrict__ tw2,
    const float* __restrict__ tb2, const int* __restrict__ tlab,
    const u16* __restrict__ a_hid, const float* __restrict__ aw2,
    const float* __restrict__ ab2, const int* __restrict__ alab,
    const u16* __restrict__ b_hid, const float* __restrict__ bw2,
    const float* __restrict__ bb2, const int* __restrict__ blab,
    float* __restrict__ out)
{
  __shared__ float w2s[256 * VV];
  int b = blockIdx.x;
  int wave = threadIdx.x >> 6, lane = threadIdx.x & 63;
  if (b < 384) {
    int r = b * 4 + wave;
    const u16* h = t_hid + (long)r * 256;
    int c = lane * 4;
    ushort4 hv = *(const ushort4*)(h + c);
    float4 wv = *(const float4*)(tw2 + c);
    float s = b2f(hv.x) * wv.x + b2f(hv.y) * wv.y + b2f(hv.z) * wv.z + b2f(hv.w) * wv.w;
#pragma unroll
    for (int off = 32; off > 0; off >>= 1) s += __shfl_xor(s, off);
    if (lane == 0) {
      float l = s + tb2[0];
      float y = (float)tlab[r];
      float sp = fmaxf(l, 0.f) + log1pf(expf(-fabsf(l)));
      atomicAdd(out, (sp - l * y) * (1.0f / BATCH));
    }
    return;
  }
  const u16* hid; const float* w2; const float* b2p; const int* lab; int NC, r;
  if (b < 704) { hid = a_hid; w2 = aw2; b2p = ab2; lab = alab; NC = VV; r = (b - 384) * 4 + wave; }
  else         { hid = b_hid; w2 = bw2; b2p = bb2; lab = blab; NC = NBOND; r = (b - 704) * 4 + wave; }
  for (int i = threadIdx.x; i < 256 * NC; i += 256) w2s[i] = w2[i];
  __syncthreads();
  const u16* h = hid + (long)r * 256;
  ushort4 hv4 = *(const ushort4*)(h + lane * 4);
  float h0 = b2f(hv4.x), h1 = b2f(hv4.y), h2 = b2f(hv4.z), h3 = b2f(hv4.w);
  bool valid = lane < NC;
  float s = valid ? b2p[lane] : 0.f;
#pragma unroll 8
  for (int j = 0; j < 64; j++) {
    float a0 = __shfl(h0, j), a1 = __shfl(h1, j), a2 = __shfl(h2, j), a3 = __shfl(h3, j);
    if (valid) {
      int c = j * 4;
      s += a0 * w2s[c * NC + lane] + a1 * w2s[(c + 1) * NC + lane]
         + a2 * w2s[(c + 2) * NC + lane] + a3 * w2s[(c + 3) * NC + lane];
    }
  }
  float logit = valid ? s : -1e30f;
  float m = logit;
#pragma unroll
  for (int off = 32; off > 0; off >>= 1) m = fmaxf(m, __shfl_xor(m, off));
  float e = valid ? expf(logit - m) : 0.f;
#pragma unroll
  for (int off = 32; off > 0; off >>= 1) e += __shfl_xor(e, off);
  float lse = m + logf(e);
  int lb = lab[r];
  float ll = __shfl(logit, lb);
  if (lane == 0) atomicAdd(out, (lse - ll) * (1.0f / BATCH));
}

// ---------------------------------------------------------------------------
extern "C" void kernel_launch(void* const* d_in, const int* in_sizes, int n_in,
                              void* d_out, int out_size, void* d_ws, size_t ws_size,
                              hipStream_t stream)
{
  const float* src      = (const float*)d_in[0];
  const float* fnode    = (const float*)d_in[1];
  const float* fmess    = (const float*)d_in[2];
  const float* W_h      = (const float*)d_in[3];
  const float* U_h      = (const float*)d_in[4];
  const float* b_h      = (const float*)d_in[5];
  const float* W_o      = (const float*)d_in[6];
  const float* b_o      = (const float*)d_in[7];
  const float* topo_w1  = (const float*)d_in[8];
  const float* topo_b1  = (const float*)d_in[9];
  const float* topo_w2  = (const float*)d_in[10];
  const float* topo_b2  = (const float*)d_in[11];
  const float* atom_w1  = (const float*)d_in[12];
  const float* atom_b1  = (const float*)d_in[13];
  const float* atom_w2  = (const float*)d_in[14];
  const float* atom_b2  = (const float*)d_in[15];
  const float* bond_w1  = (const float*)d_in[16];
  const float* bond_b1  = (const float*)d_in[17];
  const float* bond_w2  = (const float*)d_in[18];
  const float* bond_b2  = (const float*)d_in[19];
  const float* rbond_w  = (const float*)d_in[20];
  const float* rbond_b  = (const float*)d_in[21];
  const float* wbond_w  = (const float*)d_in[22];
  const float* wbond_b  = (const float*)d_in[23];
  const int* agraph     = (const int*)d_in[24];
  const int* bgraph     = (const int*)d_in[25];
  const int* node2graph = (const int*)d_in[26];
  const int* emask      = (const int*)d_in[27];
  const int* vmask      = (const int*)d_in[28];
  const int* topo_step  = (const int*)d_in[29];
  const int* topo_bid   = (const int*)d_in[30];
  const int* topo_xid   = (const int*)d_in[31];
  const int* topo_label = (const int*)d_in[32];
  const int* atom_step  = (const int*)d_in[33];
  const int* atom_bid   = (const int*)d_in[34];
  const int* atom_xid   = (const int*)d_in[35];
  const int* atom_label = (const int*)d_in[36];
  const int* bond_step  = (const int*)d_in[37];
  const int* bond_bid   = (const int*)d_in[38];
  const int* bond_zid   = (const int*)d_in[39];
  const int* bond_atype = (const int*)d_in[40];
  const int* bond_label = (const int*)d_in[41];
  const int* bond_gs    = (const int*)d_in[42];

  char* wp = (char*)d_ws;
  auto alloc = [&](size_t bytes) -> char* {
    char* p = wp; wp += (bytes + 255) & ~(size_t)255; return p;
  };
  // fixed allocations (~64 MB)
  u16* preB   = (u16*)alloc((size_t)NE * 256 * 2);
  u16* foB    = (u16*)alloc((size_t)NN * 256 * 2);
  float* gvec = (float*)alloc((size_t)TT * BATCH * 256 * 4);
  u16* Wh_t   = (u16*)alloc(256 * 256 * 2);
  u16* Uh_t   = (u16*)alloc(256 * 256 * 2);
  u16* Wo1_t  = (u16*)alloc(256 * 256 * 2);
  u16* Wo2_t  = (u16*)alloc(256 * 256 * 2);
  u16* tw1_t  = (u16*)alloc(256 * 544 * 2);
  u16* aw1_t  = (u16*)alloc(256 * 544 * 2);
  u16* bw1_t  = (u16*)alloc(256 * 800 * 2);
  u16* rw_t   = (u16*)alloc(256 * 320 * 2);
  u16* ww_t   = (u16*)alloc(256 * 288 * 2);
  u16* tva    = (u16*)alloc((size_t)(PT + PA) * 544 * 2);
  u16* bv     = (u16*)alloc((size_t)PB * 800 * 2);
  u16* wbin   = (u16*)alloc((size_t)PB * 288 * 2);
  u16* rbin   = (u16*)alloc((size_t)PB * 320 * 2);
  u16* wb     = (u16*)alloc((size_t)PB * 256 * 2);
  u16* ha_hid = (u16*)alloc((size_t)(PT + PA) * 256 * 2);
  u16* b_hid  = (u16*)alloc((size_t)PB * 256 * 2);
  u16* tv     = tva;
  u16* av     = tva + (size_t)PT * 544;
  u16* t_hid  = ha_hid;
  u16* a_hid  = ha_hid + (size_t)PT * 256;

  // chunked buffers: TB=2 preferred (ws ~220 MB total), else TB=1
  size_t used = (size_t)(wp - (char*)d_ws);
  size_t per_tb = ((size_t)(2 * NE + NN)) * 256 * 2 + 3 * 256;
  size_t remain = (ws_size > used) ? (ws_size - used) : 0;
  int TB = (remain >= 2 * per_tb) ? 2 : 1;
  u16* G     = (u16*)alloc((size_t)TB * NE * 256 * 2);  // gather out (also holds Gn)
  u16* T1    = (u16*)alloc((size_t)TB * NE * 256 * 2);  // h table
  u16* nodeB = (u16*)alloc((size_t)TB * NN * 256 * 2);

  float* out = (float*)d_out;

#define GEMM(mode, af32, Aptr, lda, M, Btptr, K, Cptr, ldc, biasp, auxp, vmp, mrows)          \
  do { dim3 g_(((M) + 127) / 128, 2);                                                         \
    gemm_bt_kernel<mode, af32><<<g_, 256, 0, stream>>>((const void*)(Aptr), (lda), (M),       \
        (Btptr), (K), (Cptr), (ldc), (biasp), (auxp), (vmp), (mrows));                        \
  } while (0)

  init_zero_kernel<<<1536, 256, 0, stream>>>(gvec, out);
  transpose_all_kernel<<<3520, 256, 0, stream>>>(W_h, U_h, W_o, topo_w1, atom_w1, bond_w1,
      rbond_w, wbond_w, Wh_t, Uh_t, Wo1_t, Wo2_t, tw1_t, aw1_t, bw1_t, rw_t, ww_t);

  // step-invariant precomputes
  GEMM(0, 1, fmess, 256, NE, Wh_t, 256, preB, 256, nullptr, nullptr, nullptr, 0);
  GEMM(0, 1, fnode, 256, NN, Wo1_t, 256, foB, 256, nullptr, nullptr, nullptr, 0);

  for (int t0 = 0; t0 < TT; t0 += TB) {
    int Me = TB * NE, Mn = TB * NN;
    // depth 2: G = gather(h1(pre));  T1 = relu(G@U_h + pre + b_h)*pad
    gather_e_kernel<1><<<TB * (NE / 8), 256, 0, stream>>>(preB, bgraph, emask, b_h, t0, G);
    GEMM(2, 0, G, 256, Me, Uh_t, 256, T1, 256, b_h, preB, nullptr, NE);
    // depth 3
    gather_e_kernel<0><<<TB * (NE / 8), 256, 0, stream>>>(T1, bgraph, emask, nullptr, t0, G);
    GEMM(2, 0, G, 256, Me, Uh_t, 256, T1, 256, b_h, preB, nullptr, NE);
    // depth 4
    gather_e_kernel<0><<<TB * (NE / 8), 256, 0, stream>>>(T1, bgraph, emask, nullptr, t0, G);
    GEMM(2, 0, G, 256, Me, Uh_t, 256, T1, 256, b_h, preB, nullptr, NE);
    // node = relu(gather_n(T1)@Wo2 + fo + b_o) * vm
    gather_n_kernel<<<TB * (NN / 8), 256, 0, stream>>>(T1, agraph, emask, t0, G);
    GEMM(3, 0, G, 256, Mn, Wo2_t, 256, nodeB, 256, b_o, foB, vmask + (size_t)t0 * NN, NN);
    // graph vectors + head-row scatter
    gvec_atomic_kernel<<<dim3(938, TB), 256, 0, stream>>>(nodeB, node2graph, gvec, t0);
    head_gather_kernel<<<1344, 256, 0, stream>>>(t0, TB, nodeB,
        topo_step, topo_xid, atom_step, atom_xid, bond_step, bond_zid,
        tv, av, bv, wbin);
  }

  // static head-input segments
  build_static_kernel<<<1344, 256, 0, stream>>>(gvec, src,
      topo_step, topo_bid, atom_step, atom_bid, bond_step, bond_bid,
      bond_label, bond_atype, tv, av, bv, wbin, rbin);

  // heads
  gemm_ta_kernel<<<dim3((PT + PA) / 128, 2), 256, 0, stream>>>(tva, tw1_t, aw1_t,
                                                               topo_b1, atom_b1, ha_hid);
  GEMM(1, 0, wbin, 288, PB, ww_t, 288, wb, 256, wbond_b, nullptr, nullptr, 0);
  hist_kernel<<<640, 256, 0, stream>>>(wb, bond_gs, bond_label, rbin);
  GEMM(1, 0, rbin, 320, PB, rw_t, 320, bv + 256, 800, rbond_b, nullptr, nullptr, 0);
  GEMM(1, 0, bv, 800, PB, bw1_t, 800, b_hid, 256, bond_b1, nullptr, nullptr, 0);

  // losses (one dispatch)
  loss_all_kernel<<<1344, 256, 0, stream>>>(
      t_hid, topo_w2, topo_b2, topo_label,
      a_hid, atom_w2, atom_b2, atom_label,
      b_hid, bond_w2, bond_b2, bond_label, out);

#undef GEMM
}

// Round 5
// 1316.191 us; speedup vs baseline: 1.3403x; 1.3403x over previous
//
#include <hip/hip_runtime.h>
#include <cstdint>
#include <cstddef>

using short8  = __attribute__((ext_vector_type(8))) short;
using floatx4 = __attribute__((ext_vector_type(4))) float;
typedef unsigned short u16;

constexpr int NN = 30000;   // nodes
constexpr int NE = 60000;   // edges / messages
constexpr int BATCH = 256;
constexpr int VV = 40;
constexpr int NBOND = 4;
constexpr int TT = 6;
constexpr int PT = 1536, PA = 1280, PB = 2560;

__device__ __forceinline__ float b2f(u16 h) {
  union { unsigned u; float f; } v; v.u = ((unsigned)h) << 16; return v.f;
}
__device__ __forceinline__ u16 f2b(float f) {
  union { float f; unsigned u; } v; v.f = f;
  unsigned r = v.u + 0x7FFFu + ((v.u >> 16) & 1u);
  return (u16)(r >> 16);
}
__device__ __forceinline__ float lo16(unsigned u) {
  union { unsigned x; float f; } v; v.x = u << 16; return v.f;
}
__device__ __forceinline__ float hi16(unsigned u) {
  union { unsigned x; float f; } v; v.x = u & 0xffff0000u; return v.f;
}
__device__ __forceinline__ unsigned pack2(float a, float b) {
  return ((unsigned)f2b(a)) | (((unsigned)f2b(b)) << 16);
}

// ---------------------------------------------------------------------------
// Full-N GEMM: C[M,256] = epi(A[M,K] @ B[K,256]), 128x256 tile, 512 threads.
// AMODE 0: A bf16 row-major (lda u16)
// AMODE 1: A f32 row-major (lda floats), converted during staging
// AMODE 2: A bf16; staged value = relu(A + abias[kcol]); row 0 -> 0  (h1 fold)
// EPI   0: C = acc     EPI 1: C = relu(acc + bias[col])
// Bt = B^T row-major bf16 [256][K].
// ---------------------------------------------------------------------------
template<int EPI, int AMODE>
__global__ __launch_bounds__(512) void gemm_n256_kernel(
    const void* __restrict__ Av, int lda, int M,
    const u16* __restrict__ Bt, int K,
    u16* __restrict__ C, int ldc,
    const float* __restrict__ bias, const float* __restrict__ abias)
{
  __shared__ __align__(16) u16 As[128][40];
  __shared__ __align__(16) u16 Bs[256][40];
  const int tid = threadIdx.x;
  const int rowbase = blockIdx.x * 128;
  const int wave = tid >> 6, lane = tid & 63;
  const int wm = wave >> 2, wn = wave & 3;
  const int lr = lane & 15, lk = (lane >> 4) * 8;
  const int arow = tid >> 2, ac8 = (tid & 3) * 8;
  const int brow = tid >> 1, bc16 = (tid & 1) * 16;

  floatx4 acc[4][4];
#pragma unroll
  for (int i = 0; i < 4; i++)
#pragma unroll
    for (int j = 0; j < 4; j++) acc[i][j] = {0.f, 0.f, 0.f, 0.f};

  for (int k0 = 0; k0 < K; k0 += 32) {
    {
      int grow = rowbase + arow;
      uint4 av = {0u, 0u, 0u, 0u};
      if (AMODE == 1) {
        if (grow < M) {
          const float* Af = (const float*)Av;
          float4 f0 = *(const float4*)(Af + (long)grow * lda + k0 + ac8);
          float4 f1 = *(const float4*)(Af + (long)grow * lda + k0 + ac8 + 4);
          av.x = pack2(f0.x, f0.y); av.y = pack2(f0.z, f0.w);
          av.z = pack2(f1.x, f1.y); av.w = pack2(f1.z, f1.w);
        }
      } else {
        if (grow < M) av = *(const uint4*)((const u16*)Av + (long)grow * lda + k0 + ac8);
        if (AMODE == 2) {
          if (grow == 0) { av = {0u, 0u, 0u, 0u}; }
          else {
            float4 b0 = *(const float4*)(abias + k0 + ac8);
            float4 b1 = *(const float4*)(abias + k0 + ac8 + 4);
            float a0 = fmaxf(lo16(av.x) + b0.x, 0.f), a1 = fmaxf(hi16(av.x) + b0.y, 0.f);
            float a2 = fmaxf(lo16(av.y) + b0.z, 0.f), a3 = fmaxf(hi16(av.y) + b0.w, 0.f);
            float a4 = fmaxf(lo16(av.z) + b1.x, 0.f), a5 = fmaxf(hi16(av.z) + b1.y, 0.f);
            float a6 = fmaxf(lo16(av.w) + b1.z, 0.f), a7 = fmaxf(hi16(av.w) + b1.w, 0.f);
            av.x = pack2(a0, a1); av.y = pack2(a2, a3);
            av.z = pack2(a4, a5); av.w = pack2(a6, a7);
          }
        }
      }
      *(uint4*)(&As[arow][ac8]) = av;
      uint4 v0 = *(const uint4*)(Bt + (long)brow * K + k0 + bc16);
      uint4 v1 = *(const uint4*)(Bt + (long)brow * K + k0 + bc16 + 8);
      *(uint4*)(&Bs[brow][bc16]) = v0;
      *(uint4*)(&Bs[brow][bc16 + 8]) = v1;
    }
    __syncthreads();
    short8 af[4], bf[4];
#pragma unroll
    for (int mt = 0; mt < 4; mt++) af[mt] = *(const short8*)(&As[wm * 64 + mt * 16 + lr][lk]);
#pragma unroll
    for (int nt = 0; nt < 4; nt++) bf[nt] = *(const short8*)(&Bs[wn * 64 + nt * 16 + lr][lk]);
#pragma unroll
    for (int mt = 0; mt < 4; mt++)
#pragma unroll
      for (int nt = 0; nt < 4; nt++)
        acc[mt][nt] = __builtin_amdgcn_mfma_f32_16x16x32_bf16(af[mt], bf[nt], acc[mt][nt], 0, 0, 0);
    __syncthreads();
  }

  const int rq = (lane >> 4) * 4;
#pragma unroll
  for (int mt = 0; mt < 4; mt++) {
#pragma unroll
    for (int nt = 0; nt < 4; nt++) {
      int gcol = wn * 64 + nt * 16 + lr;
#pragma unroll
      for (int r2 = 0; r2 < 4; r2++) {
        int grow = rowbase + wm * 64 + mt * 16 + rq + r2;
        if (grow < M) {
          float v = acc[mt][nt][r2];
          if (EPI == 1) { v += bias[gcol]; v = v > 0.f ? v : 0.f; }
          C[(long)grow * ldc + gcol] = f2b(v);
        }
      }
    }
  }
}

// ---------------------------------------------------------------------------
// 128x128-tile GEMM for the small head matrices (proven R2 path).
// MODE 0: C = acc   MODE 1: C = relu(acc + bias[col])
// ---------------------------------------------------------------------------
template<int MODE>
__global__ __launch_bounds__(256) void gemm_bt_kernel(
    const u16* __restrict__ A, int lda, int M,
    const u16* __restrict__ Bt, int K,
    u16* __restrict__ C, int ldc, const float* __restrict__ bias)
{
  __shared__ __align__(16) u16 As[128][56];
  __shared__ __align__(16) u16 Bs[128][56];
  const int tid  = threadIdx.x;
  const int wave = tid >> 6, lane = tid & 63;
  const int wm = wave >> 1, wn = wave & 1;
  const int lr = lane & 15, lk = (lane >> 4) * 8;
  const int rowbase = blockIdx.x * 128;
  const int colbase = blockIdx.y * 128;

  floatx4 acc[4][4];
#pragma unroll
  for (int i = 0; i < 4; i++)
#pragma unroll
    for (int j = 0; j < 4; j++) acc[i][j] = {0.f, 0.f, 0.f, 0.f};

  for (int k0 = 0; k0 < K; k0 += 32) {
#pragma unroll
    for (int r = 0; r < 2; r++) {
      int c = tid + 256 * r;
      int row = c >> 2, cc = (c & 3) * 8;
      int grow = rowbase + row;
      uint4 av = {0u, 0u, 0u, 0u};
      if (grow < M) av = *(const uint4*)(A + (long)grow * lda + k0 + cc);
      *(uint4*)(&As[row][cc]) = av;
      uint4 bv = *(const uint4*)(Bt + (long)(colbase + row) * K + k0 + cc);
      *(uint4*)(&Bs[row][cc]) = bv;
    }
    __syncthreads();
    short8 af[4], bf[4];
#pragma unroll
    for (int mt = 0; mt < 4; mt++) af[mt] = *(const short8*)(&As[wm * 64 + mt * 16 + lr][lk]);
#pragma unroll
    for (int nt = 0; nt < 4; nt++) bf[nt] = *(const short8*)(&Bs[wn * 64 + nt * 16 + lr][lk]);
#pragma unroll
    for (int mt = 0; mt < 4; mt++)
#pragma unroll
      for (int nt = 0; nt < 4; nt++)
        acc[mt][nt] = __builtin_amdgcn_mfma_f32_16x16x32_bf16(af[mt], bf[nt], acc[mt][nt], 0, 0, 0);
    __syncthreads();
  }

  const int rq = (lane >> 4) * 4;
#pragma unroll
  for (int mt = 0; mt < 4; mt++) {
#pragma unroll
    for (int nt = 0; nt < 4; nt++) {
      int gcol = colbase + wn * 64 + nt * 16 + lr;
#pragma unroll
      for (int r2 = 0; r2 < 4; r2++) {
        int grow = rowbase + wm * 64 + mt * 16 + rq + r2;
        if (grow < M) {
          float v = acc[mt][nt][r2];
          if (MODE == 1) { v += bias[gcol]; v = v > 0.f ? v : 0.f; }
          C[(long)grow * ldc + gcol] = f2b(v);
        }
      }
    }
  }
}

// Merged topo+atom head GEMM (K=544): rowbase<PT -> (Bt1,b1) else (Bt2,b2)
__global__ __launch_bounds__(256) void gemm_ta_kernel(
    const u16* __restrict__ A,
    const u16* __restrict__ Bt1, const u16* __restrict__ Bt2,
    const float* __restrict__ b1, const float* __restrict__ b2,
    u16* __restrict__ C)
{
  constexpr int K = 544;
  __shared__ __align__(16) u16 As[128][56];
  __shared__ __align__(16) u16 Bs[128][56];
  const int tid  = threadIdx.x;
  const int wave = tid >> 6, lane = tid & 63;
  const int wm = wave >> 1, wn = wave & 1;
  const int lr = lane & 15, lk = (lane >> 4) * 8;
  const int rowbase = blockIdx.x * 128;
  const int colbase = blockIdx.y * 128;
  const u16* Bt = (rowbase < PT) ? Bt1 : Bt2;
  const float* bias = (rowbase < PT) ? b1 : b2;

  floatx4 acc[4][4];
#pragma unroll
  for (int i = 0; i < 4; i++)
#pragma unroll
    for (int j = 0; j < 4; j++) acc[i][j] = {0.f, 0.f, 0.f, 0.f};

  for (int k0 = 0; k0 < K; k0 += 32) {
#pragma unroll
    for (int r = 0; r < 2; r++) {
      int c = tid + 256 * r;
      int row = c >> 2, cc = (c & 3) * 8;
      int grow = rowbase + row;
      uint4 av = *(const uint4*)(A + (long)grow * K + k0 + cc);
      *(uint4*)(&As[row][cc]) = av;
      uint4 bv = *(const uint4*)(Bt + (long)(colbase + row) * K + k0 + cc);
      *(uint4*)(&Bs[row][cc]) = bv;
    }
    __syncthreads();
    short8 af[4], bf[4];
#pragma unroll
    for (int mt = 0; mt < 4; mt++) af[mt] = *(const short8*)(&As[wm * 64 + mt * 16 + lr][lk]);
#pragma unroll
    for (int nt = 0; nt < 4; nt++) bf[nt] = *(const short8*)(&Bs[wn * 64 + nt * 16 + lr][lk]);
#pragma unroll
    for (int mt = 0; mt < 4; mt++)
#pragma unroll
      for (int nt = 0; nt < 4; nt++)
        acc[mt][nt] = __builtin_amdgcn_mfma_f32_16x16x32_bf16(af[mt], bf[nt], acc[mt][nt], 0, 0, 0);
    __syncthreads();
  }

  const int rq = (lane >> 4) * 4;
#pragma unroll
  for (int mt = 0; mt < 4; mt++) {
#pragma unroll
    for (int nt = 0; nt < 4; nt++) {
      int gcol = colbase + wn * 64 + nt * 16 + lr;
#pragma unroll
      for (int r2 = 0; r2 < 4; r2++) {
        int grow = rowbase + wm * 64 + mt * 16 + rq + r2;
        float v = acc[mt][nt][r2] + bias[gcol];
        v = v > 0.f ? v : 0.f;
        C[(long)grow * 256 + gcol] = f2b(v);
      }
    }
  }
}

// ---------------------------------------------------------------------------
// edge gather (R2 split): G[e] = relu(pre[e] + sum_j tab[bg(e,j)*em] + b_h) * (e>0)
// 8 rows/block, 32 threads/row, 16B/thread; emask folded into staging.
// ---------------------------------------------------------------------------
__global__ __launch_bounds__(256) void gather_e_kernel(
    const u16* __restrict__ tab, const u16* __restrict__ pre,
    const int* __restrict__ bgraph, const int* __restrict__ em_t,
    const float* __restrict__ bias, u16* __restrict__ G)
{
  int e0 = blockIdx.x * 8;
  __shared__ int sidx[8][6];
  int tid = threadIdx.x;
  if (tid < 48) {
    int rr = tid / 6, j = tid - rr * 6;
    int v = bgraph[(long)(e0 + rr) * 6 + j];
    sidx[rr][j] = v * em_t[v];
  }
  __syncthreads();
  int rl = tid >> 5, ch = (tid & 31) * 8;
  int e = e0 + rl;
  uint4 p = *(const uint4*)(pre + (long)e * 256 + ch);
  float a0 = lo16(p.x), a1 = hi16(p.x), a2 = lo16(p.y), a3 = hi16(p.y);
  float a4 = lo16(p.z), a5 = hi16(p.z), a6 = lo16(p.w), a7 = hi16(p.w);
#pragma unroll
  for (int j = 0; j < 6; j++) {
    uint4 g = *(const uint4*)(tab + (long)sidx[rl][j] * 256 + ch);
    a0 += lo16(g.x); a1 += hi16(g.x); a2 += lo16(g.y); a3 += hi16(g.y);
    a4 += lo16(g.z); a5 += hi16(g.z); a6 += lo16(g.w); a7 += hi16(g.w);
  }
  float4 b0 = *(const float4*)(bias + ch);
  float4 b1 = *(const float4*)(bias + ch + 4);
  a0 += b0.x; a1 += b0.y; a2 += b0.z; a3 += b0.w;
  a4 += b1.x; a5 += b1.y; a6 += b1.z; a7 += b1.w;
  if (e == 0) { a0 = a1 = a2 = a3 = a4 = a5 = a6 = a7 = 0.f; }
  else {
    a0 = fmaxf(a0, 0.f); a1 = fmaxf(a1, 0.f); a2 = fmaxf(a2, 0.f); a3 = fmaxf(a3, 0.f);
    a4 = fmaxf(a4, 0.f); a5 = fmaxf(a5, 0.f); a6 = fmaxf(a6, 0.f); a7 = fmaxf(a7, 0.f);
  }
  uint4 o; o.x = pack2(a0, a1); o.y = pack2(a2, a3); o.z = pack2(a4, a5); o.w = pack2(a6, a7);
  *(uint4*)(G + (long)e * 256 + ch) = o;
}

// node gather: node[n] = relu(fo[n] + sum_j tab[ag(n,j)*em] + b_o) * vm[n]
__global__ __launch_bounds__(256) void gather_n_kernel(
    const u16* __restrict__ tab, const u16* __restrict__ fo,
    const int* __restrict__ agraph, const int* __restrict__ em_t,
    const float* __restrict__ bias, const int* __restrict__ vm_t,
    u16* __restrict__ node)
{
  int n0 = blockIdx.x * 8;
  __shared__ int sidx[8][6];
  __shared__ int svm[8];
  int tid = threadIdx.x;
  if (tid < 48) {
    int rr = tid / 6, j = tid - rr * 6;
    int v = agraph[(long)(n0 + rr) * 6 + j];
    sidx[rr][j] = v * em_t[v];
  }
  if (tid >= 48 && tid < 56) svm[tid - 48] = vm_t[n0 + (tid - 48)];
  __syncthreads();
  int rl = tid >> 5, ch = (tid & 31) * 8;
  int n = n0 + rl;
  uint4 p = *(const uint4*)(fo + (long)n * 256 + ch);
  float a0 = lo16(p.x), a1 = hi16(p.x), a2 = lo16(p.y), a3 = hi16(p.y);
  float a4 = lo16(p.z), a5 = hi16(p.z), a6 = lo16(p.w), a7 = hi16(p.w);
#pragma unroll
  for (int j = 0; j < 6; j++) {
    uint4 g = *(const uint4*)(tab + (long)sidx[rl][j] * 256 + ch);
    a0 += lo16(g.x); a1 += hi16(g.x); a2 += lo16(g.y); a3 += hi16(g.y);
    a4 += lo16(g.z); a5 += hi16(g.z); a6 += lo16(g.w); a7 += hi16(g.w);
  }
  float4 b0 = *(const float4*)(bias + ch);
  float4 b1 = *(const float4*)(bias + ch + 4);
  a0 = fmaxf(a0 + b0.x, 0.f); a1 = fmaxf(a1 + b0.y, 0.f);
  a2 = fmaxf(a2 + b0.z, 0.f); a3 = fmaxf(a3 + b0.w, 0.f);
  a4 = fmaxf(a4 + b1.x, 0.f); a5 = fmaxf(a5 + b1.y, 0.f);
  a6 = fmaxf(a6 + b1.z, 0.f); a7 = fmaxf(a7 + b1.w, 0.f);
  if (svm[rl] == 0) { a0 = a1 = a2 = a3 = a4 = a5 = a6 = a7 = 0.f; }
  uint4 o; o.x = pack2(a0, a1); o.y = pack2(a2, a3); o.z = pack2(a4, a5); o.w = pack2(a6, a7);
  *(uint4*)(node + (long)n * 256 + ch) = o;
}

// zero gvec + out
__global__ __launch_bounds__(256) void init_zero_kernel(float* __restrict__ gv,
                                                        float* __restrict__ out)
{
  int i = blockIdx.x * 256 + threadIdx.x;
  gv[i] = 0.f;
  if (i == 0) out[0] = 0.f;
}

// all 9 weight transposes in one dispatch. Bt[n][k]=bf16(W[k][n]), k>=K -> 0.
__global__ __launch_bounds__(256) void transpose_all_kernel(
    const float* W_h, const float* U_h, const float* W_o,
    const float* tw1, const float* aw1, const float* bw1,
    const float* rw, const float* ww,
    u16* Wh_t, u16* Uh_t, u16* Wo1_t, u16* Wo2_t,
    u16* tw1_t, u16* aw1_t, u16* bw1_t, u16* rw_t, u16* ww_t)
{
  int b = blockIdx.x;
  const float* W; int K, Kpad; u16* Bt; int base;
  if      (b < 256)  { W = W_h;  K = 256; Kpad = 256; Bt = Wh_t;  base = 0; }
  else if (b < 512)  { W = U_h;  K = 256; Kpad = 256; Bt = Uh_t;  base = 256; }
  else if (b < 768)  { W = W_o;  K = 256; Kpad = 256; Bt = Wo1_t; base = 512; }
  else if (b < 1024) { W = W_o + 256 * 256; K = 256; Kpad = 256; Bt = Wo2_t; base = 768; }
  else if (b < 1568) { W = tw1;  K = 544; Kpad = 544; Bt = tw1_t; base = 1024; }
  else if (b < 2112) { W = aw1;  K = 544; Kpad = 544; Bt = aw1_t; base = 1568; }
  else if (b < 2912) { W = bw1;  K = 800; Kpad = 800; Bt = bw1_t; base = 2112; }
  else if (b < 3232) { W = rw;   K = 296; Kpad = 320; Bt = rw_t;  base = 2912; }
  else               { W = ww;   K = 260; Kpad = 288; Bt = ww_t;  base = 3232; }
  int idx = (b - base) * 256 + threadIdx.x;
  int n = idx / Kpad, k = idx - n * Kpad;
  Bt[idx] = (k < K) ? f2b(W[(long)k * 256 + n]) : (u16)0;
}

// segmented-sum graph vectors: 32 rows/block, atomic flush on segment change.
__global__ __launch_bounds__(256) void gvec_atomic_kernel(const u16* __restrict__ node,
                                                          const int* __restrict__ n2g,
                                                          float* __restrict__ gv)
{
  int r0 = blockIdx.x * 32;
  int h = threadIdx.x;
  int rend = r0 + 32; if (rend > NN) rend = NN;
  int gprev = n2g[r0];
  float acc = 0.f;
  for (int r = r0; r < rend; r++) {
    int g = n2g[r];
    if (g != gprev) { atomicAdd(gv + gprev * 256 + h, acc); acc = 0.f; gprev = g; }
    acc += b2f(node[(long)r * 256 + h]);
  }
  atomicAdd(gv + gprev * 256 + h, acc);
}

// scatter node rows with step == t into head-input matrices
__global__ __launch_bounds__(256) void head_gather_kernel(int t,
    const u16* __restrict__ node,
    const int* __restrict__ tstep, const int* __restrict__ txid,
    const int* __restrict__ astep, const int* __restrict__ axid,
    const int* __restrict__ bstep, const int* __restrict__ bzid,
    u16* __restrict__ tv, u16* __restrict__ av, u16* __restrict__ bv,
    u16* __restrict__ wbin)
{
  int wave = threadIdx.x >> 6, lane = threadIdx.x & 63;
  int r = blockIdx.x * 4 + wave;
  int c = lane * 4;
  if (r < PT) {
    if (tstep[r] != t) return;
    ushort4 v = *(const ushort4*)(node + (long)txid[r] * 256 + c);
    *(ushort4*)(tv + (long)r * 544 + 256 + c) = v;
  } else if (r < PT + PA) {
    int i = r - PT;
    if (astep[i] != t) return;
    ushort4 v = *(const ushort4*)(node + (long)axid[i] * 256 + c);
    *(ushort4*)(av + (long)i * 544 + 256 + c) = v;
  } else if (r < PT + PA + PB) {
    int i = r - PT - PA;
    if (bstep[i] != t) return;
    ushort4 v = *(const ushort4*)(node + (long)bzid[i] * 256 + c);
    *(ushort4*)(bv + (long)i * 800 + 512 + c) = v;
    *(ushort4*)(wbin + (long)i * 288 + c) = v;
  }
}

// fill gvec / src / one-hot segments of head inputs (after all steps)
__global__ __launch_bounds__(256) void build_static_kernel(
    const float* __restrict__ gvec, const float* __restrict__ src,
    const int* __restrict__ tstep, const int* __restrict__ tbid,
    const int* __restrict__ astep, const int* __restrict__ abid,
    const int* __restrict__ bstep, const int* __restrict__ bbid,
    const int* __restrict__ blabel, const int* __restrict__ batype,
    u16* __restrict__ tv, u16* __restrict__ av, u16* __restrict__ bv,
    u16* __restrict__ wbin, u16* __restrict__ rbin)
{
  int wave = threadIdx.x >> 6, lane = threadIdx.x & 63;
  int r = blockIdx.x * 4 + wave;
  int c = lane * 4;
  if (r < PT) {
    int st = tstep[r], bid = tbid[r];
    const float* g = gvec + ((long)st * BATCH + bid) * 256;
    u16* d = tv + (long)r * 544;
    float4 g4 = *(const float4*)(g + c);
    d[c] = f2b(g4.x); d[c + 1] = f2b(g4.y); d[c + 2] = f2b(g4.z); d[c + 3] = f2b(g4.w);
    if (lane < 8) {
      float4 s4 = *(const float4*)(src + bid * 32 + c);
      d[512 + c] = f2b(s4.x); d[512 + c + 1] = f2b(s4.y);
      d[512 + c + 2] = f2b(s4.z); d[512 + c + 3] = f2b(s4.w);
    }
  } else if (r < PT + PA) {
    int i = r - PT;
    int st = astep[i], bid = abid[i];
    const float* g = gvec + ((long)st * BATCH + bid) * 256;
    u16* d = av + (long)i * 544;
    float4 g4 = *(const float4*)(g + c);
    d[c] = f2b(g4.x); d[c + 1] = f2b(g4.y); d[c + 2] = f2b(g4.z); d[c + 3] = f2b(g4.w);
    if (lane < 8) {
      float4 s4 = *(const float4*)(src + bid * 32 + c);
      d[512 + c] = f2b(s4.x); d[512 + c + 1] = f2b(s4.y);
      d[512 + c + 2] = f2b(s4.z); d[512 + c + 3] = f2b(s4.w);
    }
  } else if (r < PT + PA + PB) {
    int i = r - PT - PA;
    int st = bstep[i], bid = bbid[i];
    const float* g = gvec + ((long)st * BATCH + bid) * 256;
    u16* d = bv + (long)i * 800;
    float4 g4 = *(const float4*)(g + c);
    d[c] = f2b(g4.x); d[c + 1] = f2b(g4.y); d[c + 2] = f2b(g4.z); d[c + 3] = f2b(g4.w);
    if (lane < 8) {
      float4 s4 = *(const float4*)(src + bid * 32 + c);
      d[768 + c] = f2b(s4.x); d[768 + c + 1] = f2b(s4.y);
      d[768 + c + 2] = f2b(s4.z); d[768 + c + 3] = f2b(s4.w);
      int bl = blabel[i];
      u16* wd = wbin + (long)i * 288 + 256;
      for (int q = 0; q < 4; q++) {
        int k = c + q;
        wd[k] = f2b((k < NBOND && bl == k) ? 1.f : 0.f);
      }
    }
    if (lane < 16) {
      int at = batype[i];
      u16* rd = rbin + (long)i * 320 + 256;
      for (int q = 0; q < 4; q++) {
        int k = c + q;
        rd[k] = f2b((k < VV && at == k) ? 1.f : 0.f);
      }
    }
  }
}

// rbin[r][0:256] = sum_{j in [gs[r], r)} wb[j] * (blabel[j] > 0)
__global__ __launch_bounds__(256) void hist_kernel(
    const u16* __restrict__ wb, const int* __restrict__ gs_arr,
    const int* __restrict__ blabel, u16* __restrict__ rbin)
{
  int wave = threadIdx.x >> 6, lane = threadIdx.x & 63;
  int r = blockIdx.x * 4 + wave;
  if (r >= PB) return;
  int c = lane * 4;
  float a0 = 0.f, a1 = 0.f, a2 = 0.f, a3 = 0.f;
  int gs = gs_arr[r];
  for (int j = gs; j < r; j++) {
    if (blabel[j] > 0) {
      ushort4 g = *(const ushort4*)(wb + (long)j * 256 + c);
      a0 += b2f(g.x); a1 += b2f(g.y); a2 += b2f(g.z); a3 += b2f(g.w);
    }
  }
  u16* rd = rbin + (long)r * 320;
  rd[c] = f2b(a0); rd[c + 1] = f2b(a1); rd[c + 2] = f2b(a2); rd[c + 3] = f2b(a3);
}

// all three losses in one dispatch:
// blocks [0,384): topo BCE; [384,704): atom CE (NC=40); [704,1344): bond CE (NC=4)
__global__ __launch_bounds__(256) void loss_all_kernel(
    const u16* __restrict__ t_hid, const float* __restrict__ tw2,
    const float* __restrict__ tb2, const int* __restrict__ tlab,
    const u16* __restrict__ a_hid, const float* __restrict__ aw2,
    const float* __restrict__ ab2, const int* __restrict__ alab,
    const u16* __restrict__ b_hid, const float* __restrict__ bw2,
    const float* __restrict__ bb2, const int* __restrict__ blab,
    float* __restrict__ out)
{
  __shared__ float w2s[256 * VV];
  int b = blockIdx.x;
  int wave = threadIdx.x >> 6, lane = threadIdx.x & 63;
  if (b < 384) {
    int r = b * 4 + wave;
    const u16* h = t_hid + (long)r * 256;
    int c = lane * 4;
    ushort4 hv = *(const ushort4*)(h + c);
    float4 wv = *(const float4*)(tw2 + c);
    float s = b2f(hv.x) * wv.x + b2f(hv.y) * wv.y + b2f(hv.z) * wv.z + b2f(hv.w) * wv.w;
#pragma unroll
    for (int off = 32; off > 0; off >>= 1) s += __shfl_xor(s, off);
    if (lane == 0) {
      float l = s + tb2[0];
      float y = (float)tlab[r];
      float sp = fmaxf(l, 0.f) + log1pf(expf(-fabsf(l)));
      atomicAdd(out, (sp - l * y) * (1.0f / BATCH));
    }
    return;
  }
  const u16* hid; const float* w2; const float* b2p; const int* lab; int NC, r;
  if (b < 704) { hid = a_hid; w2 = aw2; b2p = ab2; lab = alab; NC = VV; r = (b - 384) * 4 + wave; }
  else         { hid = b_hid; w2 = bw2; b2p = bb2; lab = blab; NC = NBOND; r = (b - 704) * 4 + wave; }
  for (int i = threadIdx.x; i < 256 * NC; i += 256) w2s[i] = w2[i];
  __syncthreads();
  const u16* h = hid + (long)r * 256;
  ushort4 hv4 = *(const ushort4*)(h + lane * 4);
  float h0 = b2f(hv4.x), h1 = b2f(hv4.y), h2 = b2f(hv4.z), h3 = b2f(hv4.w);
  bool valid = lane < NC;
  float s = valid ? b2p[lane] : 0.f;
#pragma unroll 8
  for (int j = 0; j < 64; j++) {
    float a0 = __shfl(h0, j), a1 = __shfl(h1, j), a2 = __shfl(h2, j), a3 = __shfl(h3, j);
    if (valid) {
      int c = j * 4;
      s += a0 * w2s[c * NC + lane] + a1 * w2s[(c + 1) * NC + lane]
         + a2 * w2s[(c + 2) * NC + lane] + a3 * w2s[(c + 3) * NC + lane];
    }
  }
  float logit = valid ? s : -1e30f;
  float m = logit;
#pragma unroll
  for (int off = 32; off > 0; off >>= 1) m = fmaxf(m, __shfl_xor(m, off));
  float e = valid ? expf(logit - m) : 0.f;
#pragma unroll
  for (int off = 32; off > 0; off >>= 1) e += __shfl_xor(e, off);
  float lse = m + logf(e);
  int lb = lab[r];
  float ll = __shfl(logit, lb);
  if (lane == 0) atomicAdd(out, (lse - ll) * (1.0f / BATCH));
}

// ---------------------------------------------------------------------------
extern "C" void kernel_launch(void* const* d_in, const int* in_sizes, int n_in,
                              void* d_out, int out_size, void* d_ws, size_t ws_size,
                              hipStream_t stream)
{
  const float* src      = (const float*)d_in[0];
  const float* fnode    = (const float*)d_in[1];
  const float* fmess    = (const float*)d_in[2];
  const float* W_h      = (const float*)d_in[3];
  const float* U_h      = (const float*)d_in[4];
  const float* b_h      = (const float*)d_in[5];
  const float* W_o      = (const float*)d_in[6];
  const float* b_o      = (const float*)d_in[7];
  const float* topo_w1  = (const float*)d_in[8];
  const float* topo_b1  = (const float*)d_in[9];
  const float* topo_w2  = (const float*)d_in[10];
  const float* topo_b2  = (const float*)d_in[11];
  const float* atom_w1  = (const float*)d_in[12];
  const float* atom_b1  = (const float*)d_in[13];
  const float* atom_w2  = (const float*)d_in[14];
  const float* atom_b2  = (const float*)d_in[15];
  const float* bond_w1  = (const float*)d_in[16];
  const float* bond_b1  = (const float*)d_in[17];
  const float* bond_w2  = (const float*)d_in[18];
  const float* bond_b2  = (const float*)d_in[19];
  const float* rbond_w  = (const float*)d_in[20];
  const float* rbond_b  = (const float*)d_in[21];
  const float* wbond_w  = (const float*)d_in[22];
  const float* wbond_b  = (const float*)d_in[23];
  const int* agraph     = (const int*)d_in[24];
  const int* bgraph     = (const int*)d_in[25];
  const int* node2graph = (const int*)d_in[26];
  const int* emask      = (const int*)d_in[27];
  const int* vmask      = (const int*)d_in[28];
  const int* topo_step  = (const int*)d_in[29];
  const int* topo_bid   = (const int*)d_in[30];
  const int* topo_xid   = (const int*)d_in[31];
  const int* topo_label = (const int*)d_in[32];
  const int* atom_step  = (const int*)d_in[33];
  const int* atom_bid   = (const int*)d_in[34];
  const int* atom_xid   = (const int*)d_in[35];
  const int* atom_label = (const int*)d_in[36];
  const int* bond_step  = (const int*)d_in[37];
  const int* bond_bid   = (const int*)d_in[38];
  const int* bond_zid   = (const int*)d_in[39];
  const int* bond_atype = (const int*)d_in[40];
  const int* bond_label = (const int*)d_in[41];
  const int* bond_gs    = (const int*)d_in[42];

  char* wp = (char*)d_ws;
  auto alloc = [&](size_t bytes) -> char* {
    char* p = wp; wp += (bytes + 255) & ~(size_t)255; return p;
  };
  // total ~160 MB -> loop working set fits the 256 MB Infinity Cache
  u16* preB   = (u16*)alloc((size_t)NE * 256 * 2);   // 30.7 MB
  u16* hu1B   = (u16*)alloc((size_t)NE * 256 * 2);   // 30.7 MB
  u16* foB    = (u16*)alloc((size_t)NN * 256 * 2);   // 15.4 MB
  u16* G      = (u16*)alloc((size_t)NE * 256 * 2);   // 30.7 MB (also nodeB alias)
  u16* T      = (u16*)alloc((size_t)NE * 256 * 2);   // 30.7 MB
  float* gvec = (float*)alloc((size_t)TT * BATCH * 256 * 4);
  u16* Wh_t   = (u16*)alloc(256 * 256 * 2);
  u16* Uh_t   = (u16*)alloc(256 * 256 * 2);
  u16* Wo1_t  = (u16*)alloc(256 * 256 * 2);
  u16* Wo2_t  = (u16*)alloc(256 * 256 * 2);
  u16* tw1_t  = (u16*)alloc(256 * 544 * 2);
  u16* aw1_t  = (u16*)alloc(256 * 544 * 2);
  u16* bw1_t  = (u16*)alloc(256 * 800 * 2);
  u16* rw_t   = (u16*)alloc(256 * 320 * 2);
  u16* ww_t   = (u16*)alloc(256 * 288 * 2);
  u16* tva    = (u16*)alloc((size_t)(PT + PA) * 544 * 2);
  u16* bv     = (u16*)alloc((size_t)PB * 800 * 2);
  u16* wbin   = (u16*)alloc((size_t)PB * 288 * 2);
  u16* rbin   = (u16*)alloc((size_t)PB * 320 * 2);
  u16* wb     = (u16*)alloc((size_t)PB * 256 * 2);
  u16* ha_hid = (u16*)alloc((size_t)(PT + PA) * 256 * 2);
  u16* b_hid  = (u16*)alloc((size_t)PB * 256 * 2);
  u16* tv     = tva;
  u16* av     = tva + (size_t)PT * 544;
  u16* t_hid  = ha_hid;
  u16* a_hid  = ha_hid + (size_t)PT * 256;
  u16* nodeB  = G;   // alias: G is free when gather_n runs

  float* out = (float*)d_out;

  init_zero_kernel<<<1536, 256, 0, stream>>>(gvec, out);
  transpose_all_kernel<<<3520, 256, 0, stream>>>(W_h, U_h, W_o, topo_w1, atom_w1, bond_w1,
      rbond_w, wbond_w, Wh_t, Uh_t, Wo1_t, Wo2_t, tw1_t, aw1_t, bw1_t, rw_t, ww_t);

  // step-invariant precomputes
  gemm_n256_kernel<0, 1><<<(NE + 127) / 128, 512, 0, stream>>>(
      fmess, 256, NE, Wh_t, 256, preB, 256, nullptr, nullptr);      // pre = fmess @ W_h
  gemm_n256_kernel<0, 1><<<(NN + 127) / 128, 512, 0, stream>>>(
      fnode, 256, NN, Wo1_t, 256, foB, 256, nullptr, nullptr);      // fo = fnode @ W_o[:256]
  gemm_n256_kernel<0, 2><<<(NE + 127) / 128, 512, 0, stream>>>(
      preB, 256, NE, Uh_t, 256, hu1B, 256, nullptr, b_h);           // hu1 = h1 @ U_h (h1 folded)

  for (int t = 0; t < TT; t++) {
    const int* em_t = emask + (size_t)t * NE;
    // depth 2..4: gather (h_{d+1}) then GEMM (@U or @Wo2)
    gather_e_kernel<<<NE / 8, 256, 0, stream>>>(hu1B, preB, bgraph, em_t, b_h, G);
    gemm_n256_kernel<0, 0><<<(NE + 127) / 128, 512, 0, stream>>>(
        G, 256, NE, Uh_t, 256, T, 256, nullptr, nullptr);
    gather_e_kernel<<<NE / 8, 256, 0, stream>>>(T, preB, bgraph, em_t, b_h, G);
    gemm_n256_kernel<0, 0><<<(NE + 127) / 128, 512, 0, stream>>>(
        G, 256, NE, Uh_t, 256, T, 256, nullptr, nullptr);
    gather_e_kernel<<<NE / 8, 256, 0, stream>>>(T, preB, bgraph, em_t, b_h, G);
    gemm_n256_kernel<0, 0><<<(NE + 127) / 128, 512, 0, stream>>>(
        G, 256, NE, Wo2_t, 256, T, 256, nullptr, nullptr);          // h4 @ W_o[256:]
    // node = relu(fo + gather_n(T) + b_o) * vm   (writes nodeB == G)
    gather_n_kernel<<<NN / 8 + 1, 256, 0, stream>>>(T, foB, agraph, em_t, b_o,
                                                    vmask + (size_t)t * NN, nodeB);
    gvec_atomic_kernel<<<938, 256, 0, stream>>>(nodeB, node2graph,
                                                gvec + (size_t)t * BATCH * 256);
    head_gather_kernel<<<1344, 256, 0, stream>>>(t, nodeB,
        topo_step, topo_xid, atom_step, atom_xid, bond_step, bond_zid,
        tv, av, bv, wbin);
  }

  // static head-input segments
  build_static_kernel<<<1344, 256, 0, stream>>>(gvec, src,
      topo_step, topo_bid, atom_step, atom_bid, bond_step, bond_bid,
      bond_label, bond_atype, tv, av, bv, wbin, rbin);

  // heads
  gemm_ta_kernel<<<dim3((PT + PA) / 128, 2), 256, 0, stream>>>(tva, tw1_t, aw1_t,
                                                               topo_b1, atom_b1, ha_hid);
  gemm_bt_kernel<1><<<dim3(20, 2), 256, 0, stream>>>(wbin, 288, PB, ww_t, 288,
                                                     wb, 256, wbond_b);
  hist_kernel<<<640, 256, 0, stream>>>(wb, bond_gs, bond_label, rbin);
  gemm_bt_kernel<1><<<dim3(20, 2), 256, 0, stream>>>(rbin, 320, PB, rw_t, 320,
                                                     bv + 256, 800, rbond_b);
  gemm_bt_kernel<1><<<dim3(20, 2), 256, 0, stream>>>(bv, 800, PB, bw1_t, 800,
                                                     b_hid, 256, bond_b1);

  // losses (one dispatch)
  loss_all_kernel<<<1344, 256, 0, stream>>>(
      t_hid, topo_w2, topo_b2, topo_label,
      a_hid, atom_w2, atom_b2, atom_label,
      b_hid, bond_w2, bond_b2, bond_label, out);
}

// Round 6
// 1140.074 us; speedup vs baseline: 1.5474x; 1.1545x over previous
//
#include <hip/hip_runtime.h>
#include <cstdint>
#include <cstddef>

using short8  = __attribute__((ext_vector_type(8))) short;
using floatx4 = __attribute__((ext_vector_type(4))) float;
typedef unsigned short u16;

constexpr int NN = 30000;   // nodes
constexpr int NE = 60000;   // edges / messages
constexpr int BATCH = 256;
constexpr int VV = 40;
constexpr int NBOND = 4;
constexpr int TT = 6;
constexpr int PT = 1536, PA = 1280, PB = 2560;
constexpr int PALL = PT + PA + PB;   // 5376

__device__ __forceinline__ float b2f(u16 h) {
  union { unsigned u; float f; } v; v.u = ((unsigned)h) << 16; return v.f;
}
__device__ __forceinline__ u16 f2b(float f) {
  union { float f; unsigned u; } v; v.f = f;
  unsigned r = v.u + 0x7FFFu + ((v.u >> 16) & 1u);
  return (u16)(r >> 16);
}
__device__ __forceinline__ float lo16(unsigned u) {
  union { unsigned x; float f; } v; v.x = u << 16; return v.f;
}
__device__ __forceinline__ float hi16(unsigned u) {
  union { unsigned x; float f; } v; v.x = u & 0xffff0000u; return v.f;
}
__device__ __forceinline__ unsigned pack2(float a, float b) {
  return ((unsigned)f2b(a)) | (((unsigned)f2b(b)) << 16);
}

// ---------------------------------------------------------------------------
// Full-N GEMM: C[M,256] = A[M,K] @ B[K,256], 128x256 tile, 512 threads.
// AMODE 0: A bf16  AMODE 1: A f32 (convert in staging)
// AMODE 2: A bf16; staged = relu(A + abias[kcol]); row 0 -> 0   (h1 fold)
// ---------------------------------------------------------------------------
template<int AMODE>
__global__ __launch_bounds__(512) void gemm_n256_kernel(
    const void* __restrict__ Av, int M,
    const u16* __restrict__ Bt,
    u16* __restrict__ C, const float* __restrict__ abias)
{
  __shared__ __align__(16) u16 As[128][40];
  __shared__ __align__(16) u16 Bs[256][40];
  const int tid = threadIdx.x;
  const int rowbase = blockIdx.x * 128;
  const int wave = tid >> 6, lane = tid & 63;
  const int wm = wave >> 2, wn = wave & 3;
  const int lr = lane & 15, lk = (lane >> 4) * 8;
  const int arow = tid >> 2, ac8 = (tid & 3) * 8;
  const int brow = tid >> 1, bc16 = (tid & 1) * 16;

  floatx4 acc[4][4];
#pragma unroll
  for (int i = 0; i < 4; i++)
#pragma unroll
    for (int j = 0; j < 4; j++) acc[i][j] = {0.f, 0.f, 0.f, 0.f};

  for (int k0 = 0; k0 < 256; k0 += 32) {
    {
      int grow = rowbase + arow;
      uint4 av = {0u, 0u, 0u, 0u};
      if (AMODE == 1) {
        if (grow < M) {
          const float* Af = (const float*)Av;
          float4 f0 = *(const float4*)(Af + (long)grow * 256 + k0 + ac8);
          float4 f1 = *(const float4*)(Af + (long)grow * 256 + k0 + ac8 + 4);
          av.x = pack2(f0.x, f0.y); av.y = pack2(f0.z, f0.w);
          av.z = pack2(f1.x, f1.y); av.w = pack2(f1.z, f1.w);
        }
      } else {
        if (grow < M) av = *(const uint4*)((const u16*)Av + (long)grow * 256 + k0 + ac8);
        if (AMODE == 2) {
          if (grow == 0) { av = {0u, 0u, 0u, 0u}; }
          else {
            float4 b0 = *(const float4*)(abias + k0 + ac8);
            float4 b1 = *(const float4*)(abias + k0 + ac8 + 4);
            float a0 = fmaxf(lo16(av.x) + b0.x, 0.f), a1 = fmaxf(hi16(av.x) + b0.y, 0.f);
            float a2 = fmaxf(lo16(av.y) + b0.z, 0.f), a3 = fmaxf(hi16(av.y) + b0.w, 0.f);
            float a4 = fmaxf(lo16(av.z) + b1.x, 0.f), a5 = fmaxf(hi16(av.z) + b1.y, 0.f);
            float a6 = fmaxf(lo16(av.w) + b1.z, 0.f), a7 = fmaxf(hi16(av.w) + b1.w, 0.f);
            av.x = pack2(a0, a1); av.y = pack2(a2, a3);
            av.z = pack2(a4, a5); av.w = pack2(a6, a7);
          }
        }
      }
      *(uint4*)(&As[arow][ac8]) = av;
      uint4 v0 = *(const uint4*)(Bt + (long)brow * 256 + k0 + bc16);
      uint4 v1 = *(const uint4*)(Bt + (long)brow * 256 + k0 + bc16 + 8);
      *(uint4*)(&Bs[brow][bc16]) = v0;
      *(uint4*)(&Bs[brow][bc16 + 8]) = v1;
    }
    __syncthreads();
    short8 af[4], bf[4];
#pragma unroll
    for (int mt = 0; mt < 4; mt++) af[mt] = *(const short8*)(&As[wm * 64 + mt * 16 + lr][lk]);
#pragma unroll
    for (int nt = 0; nt < 4; nt++) bf[nt] = *(const short8*)(&Bs[wn * 64 + nt * 16 + lr][lk]);
#pragma unroll
    for (int mt = 0; mt < 4; mt++)
#pragma unroll
      for (int nt = 0; nt < 4; nt++)
        acc[mt][nt] = __builtin_amdgcn_mfma_f32_16x16x32_bf16(af[mt], bf[nt], acc[mt][nt], 0, 0, 0);
    __syncthreads();
  }

  const int rq = (lane >> 4) * 4;
#pragma unroll
  for (int mt = 0; mt < 4; mt++) {
#pragma unroll
    for (int nt = 0; nt < 4; nt++) {
      int gcol = wn * 64 + nt * 16 + lr;
#pragma unroll
      for (int r2 = 0; r2 < 4; r2++) {
        int grow = rowbase + wm * 64 + mt * 16 + rq + r2;
        if (grow < M) C[(long)grow * 256 + gcol] = f2b(acc[mt][nt][r2]);
      }
    }
  }
}

// ---------------------------------------------------------------------------
// 128x128-tile GEMM for the head matrices. MODE 0: plain  MODE 1: relu+bias
// ---------------------------------------------------------------------------
template<int MODE>
__global__ __launch_bounds__(256) void gemm_bt_kernel(
    const u16* __restrict__ A, int lda, int M,
    const u16* __restrict__ Bt, int K,
    u16* __restrict__ C, int ldc, const float* __restrict__ bias)
{
  __shared__ __align__(16) u16 As[128][56];
  __shared__ __align__(16) u16 Bs[128][56];
  const int tid  = threadIdx.x;
  const int wave = tid >> 6, lane = tid & 63;
  const int wm = wave >> 1, wn = wave & 1;
  const int lr = lane & 15, lk = (lane >> 4) * 8;
  const int rowbase = blockIdx.x * 128;
  const int colbase = blockIdx.y * 128;

  floatx4 acc[4][4];
#pragma unroll
  for (int i = 0; i < 4; i++)
#pragma unroll
    for (int j = 0; j < 4; j++) acc[i][j] = {0.f, 0.f, 0.f, 0.f};

  for (int k0 = 0; k0 < K; k0 += 32) {
#pragma unroll
    for (int r = 0; r < 2; r++) {
      int c = tid + 256 * r;
      int row = c >> 2, cc = (c & 3) * 8;
      int grow = rowbase + row;
      uint4 av = {0u, 0u, 0u, 0u};
      if (grow < M) av = *(const uint4*)(A + (long)grow * lda + k0 + cc);
      *(uint4*)(&As[row][cc]) = av;
      uint4 bv = *(const uint4*)(Bt + (long)(colbase + row) * K + k0 + cc);
      *(uint4*)(&Bs[row][cc]) = bv;
    }
    __syncthreads();
    short8 af[4], bf[4];
#pragma unroll
    for (int mt = 0; mt < 4; mt++) af[mt] = *(const short8*)(&As[wm * 64 + mt * 16 + lr][lk]);
#pragma unroll
    for (int nt = 0; nt < 4; nt++) bf[nt] = *(const short8*)(&Bs[wn * 64 + nt * 16 + lr][lk]);
#pragma unroll
    for (int mt = 0; mt < 4; mt++)
#pragma unroll
      for (int nt = 0; nt < 4; nt++)
        acc[mt][nt] = __builtin_amdgcn_mfma_f32_16x16x32_bf16(af[mt], bf[nt], acc[mt][nt], 0, 0, 0);
    __syncthreads();
  }

  const int rq = (lane >> 4) * 4;
#pragma unroll
  for (int mt = 0; mt < 4; mt++) {
#pragma unroll
    for (int nt = 0; nt < 4; nt++) {
      int gcol = colbase + wn * 64 + nt * 16 + lr;
#pragma unroll
      for (int r2 = 0; r2 < 4; r2++) {
        int grow = rowbase + wm * 64 + mt * 16 + rq + r2;
        if (grow < M) {
          float v = acc[mt][nt][r2];
          if (MODE == 1) { v += bias[gcol]; v = v > 0.f ? v : 0.f; }
          C[(long)grow * ldc + gcol] = f2b(v);
        }
      }
    }
  }
}

// Merged topo+atom head GEMM (K=544): rowbase<PT -> (Bt1,b1) else (Bt2,b2)
__global__ __launch_bounds__(256) void gemm_ta_kernel(
    const u16* __restrict__ A,
    const u16* __restrict__ Bt1, const u16* __restrict__ Bt2,
    const float* __restrict__ b1, const float* __restrict__ b2,
    u16* __restrict__ C)
{
  constexpr int K = 544;
  __shared__ __align__(16) u16 As[128][56];
  __shared__ __align__(16) u16 Bs[128][56];
  const int tid  = threadIdx.x;
  const int wave = tid >> 6, lane = tid & 63;
  const int wm = wave >> 1, wn = wave & 1;
  const int lr = lane & 15, lk = (lane >> 4) * 8;
  const int rowbase = blockIdx.x * 128;
  const int colbase = blockIdx.y * 128;
  const u16* Bt = (rowbase < PT) ? Bt1 : Bt2;
  const float* bias = (rowbase < PT) ? b1 : b2;

  floatx4 acc[4][4];
#pragma unroll
  for (int i = 0; i < 4; i++)
#pragma unroll
    for (int j = 0; j < 4; j++) acc[i][j] = {0.f, 0.f, 0.f, 0.f};

  for (int k0 = 0; k0 < K; k0 += 32) {
#pragma unroll
    for (int r = 0; r < 2; r++) {
      int c = tid + 256 * r;
      int row = c >> 2, cc = (c & 3) * 8;
      int grow = rowbase + row;
      uint4 av = *(const uint4*)(A + (long)grow * K + k0 + cc);
      *(uint4*)(&As[row][cc]) = av;
      uint4 bv = *(const uint4*)(Bt + (long)(colbase + row) * K + k0 + cc);
      *(uint4*)(&Bs[row][cc]) = bv;
    }
    __syncthreads();
    short8 af[4], bf[4];
#pragma unroll
    for (int mt = 0; mt < 4; mt++) af[mt] = *(const short8*)(&As[wm * 64 + mt * 16 + lr][lk]);
#pragma unroll
    for (int nt = 0; nt < 4; nt++) bf[nt] = *(const short8*)(&Bs[wn * 64 + nt * 16 + lr][lk]);
#pragma unroll
    for (int mt = 0; mt < 4; mt++)
#pragma unroll
      for (int nt = 0; nt < 4; nt++)
        acc[mt][nt] = __builtin_amdgcn_mfma_f32_16x16x32_bf16(af[mt], bf[nt], acc[mt][nt], 0, 0, 0);
    __syncthreads();
  }

  const int rq = (lane >> 4) * 4;
#pragma unroll
  for (int mt = 0; mt < 4; mt++) {
#pragma unroll
    for (int nt = 0; nt < 4; nt++) {
      int gcol = colbase + wn * 64 + nt * 16 + lr;
#pragma unroll
      for (int r2 = 0; r2 < 4; r2++) {
        int grow = rowbase + wm * 64 + mt * 16 + rq + r2;
        float v = acc[mt][nt][r2] + bias[gcol];
        v = v > 0.f ? v : 0.f;
        C[(long)grow * 256 + gcol] = f2b(v);
      }
    }
  }
}

// ---------------------------------------------------------------------------
// Logits GEMM: L[5376,64] = hid_all @ w2c[seg] + b2c[seg]   (f32 out)
// 128x64 tile, 256 threads, K=256; seg picked per 128-row block.
// ---------------------------------------------------------------------------
__global__ __launch_bounds__(256) void gemm_logits_kernel(
    const u16* __restrict__ A, const u16* __restrict__ w2c,
    const float* __restrict__ b2c, float* __restrict__ L)
{
  __shared__ __align__(16) u16 As[128][40];
  __shared__ __align__(16) u16 Bs[64][40];
  const int tid = threadIdx.x;
  const int rowbase = blockIdx.x * 128;
  const int seg = (rowbase < PT) ? 0 : (rowbase < PT + PA ? 1 : 2);
  const u16* Bt = w2c + seg * 64 * 256;
  const int wave = tid >> 6, lane = tid & 63;
  const int wm = wave >> 1, wn = wave & 1;
  const int lr = lane & 15, lk = (lane >> 4) * 8;
  const int sr = tid >> 2, sc = (tid & 3) * 8;

  floatx4 acc[4][2];
#pragma unroll
  for (int i = 0; i < 4; i++)
#pragma unroll
    for (int j = 0; j < 2; j++) acc[i][j] = {0.f, 0.f, 0.f, 0.f};

  for (int k0 = 0; k0 < 256; k0 += 32) {
    *(uint4*)(&As[sr][sc]) = *(const uint4*)(A + (long)(rowbase + sr) * 256 + k0 + sc);
    *(uint4*)(&As[sr + 64][sc]) = *(const uint4*)(A + (long)(rowbase + sr + 64) * 256 + k0 + sc);
    *(uint4*)(&Bs[sr][sc]) = *(const uint4*)(Bt + (long)sr * 256 + k0 + sc);
    __syncthreads();
    short8 af[4], bf[2];
#pragma unroll
    for (int mt = 0; mt < 4; mt++) af[mt] = *(const short8*)(&As[wm * 64 + mt * 16 + lr][lk]);
#pragma unroll
    for (int nt = 0; nt < 2; nt++) bf[nt] = *(const short8*)(&Bs[wn * 32 + nt * 16 + lr][lk]);
#pragma unroll
    for (int mt = 0; mt < 4; mt++)
#pragma unroll
      for (int nt = 0; nt < 2; nt++)
        acc[mt][nt] = __builtin_amdgcn_mfma_f32_16x16x32_bf16(af[mt], bf[nt], acc[mt][nt], 0, 0, 0);
    __syncthreads();
  }

  const int rq = (lane >> 4) * 4;
#pragma unroll
  for (int mt = 0; mt < 4; mt++) {
#pragma unroll
    for (int nt = 0; nt < 2; nt++) {
      int gcol = wn * 32 + nt * 16 + lr;
#pragma unroll
      for (int r2 = 0; r2 < 4; r2++) {
        int grow = rowbase + wm * 64 + mt * 16 + rq + r2;
        L[(long)grow * 64 + gcol] = acc[mt][nt][r2] + b2c[seg * 64 + gcol];
      }
    }
  }
}

// build combined second-layer weights (bf16, Bt layout) + biases
__global__ __launch_bounds__(256) void build_w2c_kernel(
    const float* __restrict__ tw2, const float* __restrict__ tb2,
    const float* __restrict__ aw2, const float* __restrict__ ab2,
    const float* __restrict__ bw2, const float* __restrict__ bb2,
    u16* __restrict__ w2c, float* __restrict__ b2c)
{
  int idx = blockIdx.x * 256 + threadIdx.x;           // [0, 3*64*256)
  int seg = idx / 16384;
  int rem = idx - seg * 16384;
  int n = rem >> 8, k = rem & 255;
  const float* W; const float* B; int NC;
  if (seg == 0)      { W = tw2; B = tb2; NC = 1; }
  else if (seg == 1) { W = aw2; B = ab2; NC = VV; }
  else               { W = bw2; B = bb2; NC = NBOND; }
  w2c[idx] = (n < NC) ? f2b(W[(long)k * NC + n]) : (u16)0;
  if (idx < 192) {
    int s2 = idx / 64, n2 = idx & 63;
    const float* B2 = (s2 == 0) ? tb2 : (s2 == 1 ? ab2 : bb2);
    int NC2 = (s2 == 0) ? 1 : (s2 == 1 ? VV : NBOND);
    b2c[idx] = (n2 < NC2) ? B2[n2] : 0.f;
  }
}

// final loss from logits: 1344 blocks x 4 rows; one atomic per block
__global__ __launch_bounds__(256) void loss_finalize_kernel(
    const float* __restrict__ L,
    const int* __restrict__ tlab, const int* __restrict__ alab,
    const int* __restrict__ blab, float* __restrict__ out)
{
  __shared__ float part[4];
  int wave = threadIdx.x >> 6, lane = threadIdx.x & 63;
  int r = blockIdx.x * 4 + wave;
  float contrib = 0.f;
  if (r < PT) {
    float l = L[(long)r * 64];
    float y = (float)tlab[r];
    contrib = fmaxf(l, 0.f) + log1pf(expf(-fabsf(l))) - l * y;
  } else {
    int NC, lb;
    if (r < PT + PA) { NC = VV; lb = alab[r - PT]; }
    else             { NC = NBOND; lb = blab[r - PT - PA]; }
    bool valid = lane < NC;
    float logit = valid ? L[(long)r * 64 + lane] : -1e30f;
    float m = logit;
#pragma unroll
    for (int off = 32; off > 0; off >>= 1) m = fmaxf(m, __shfl_xor(m, off));
    float e = valid ? expf(logit - m) : 0.f;
#pragma unroll
    for (int off = 32; off > 0; off >>= 1) e += __shfl_xor(e, off);
    float lse = m + logf(e);
    float ll = __shfl(logit, lb);
    contrib = lse - ll;
  }
  if (lane == 0) part[wave] = contrib;
  __syncthreads();
  if (threadIdx.x == 0)
    atomicAdd(out, (part[0] + part[1] + part[2] + part[3]) * (1.0f / BATCH));
}

// ---------------------------------------------------------------------------
// TB=2 gathers: 8 rows/block, 32 threads/row, 16B/thread; emask folded in.
// SHARED_TAB=1: tab step-invariant (hu1B); 0: tab = T chunk (row tl*NE + idx)
// ---------------------------------------------------------------------------
template<int SHARED_TAB>
__global__ __launch_bounds__(256) void gather_e2_kernel(
    const u16* __restrict__ tab, const u16* __restrict__ pre,
    const int* __restrict__ bgraph, const int* __restrict__ emask,
    const float* __restrict__ bias, int t0, u16* __restrict__ G)
{
  int r0 = blockIdx.x * 8;
  int tl = r0 / NE;
  int e0 = r0 - tl * NE;
  const int* em_t = emask + (long)(t0 + tl) * NE;
  __shared__ int sidx[8][6];
  int tid = threadIdx.x;
  if (tid < 48) {
    int rr = tid / 6, j = tid - rr * 6;
    int v = bgraph[(long)(e0 + rr) * 6 + j];
    v = v * em_t[v];
    sidx[rr][j] = SHARED_TAB ? v : (tl * NE + v);
  }
  __syncthreads();
  int rl = tid >> 5, ch = (tid & 31) * 8;
  int e = e0 + rl;
  uint4 p = *(const uint4*)(pre + (long)e * 256 + ch);
  float a0 = lo16(p.x), a1 = hi16(p.x), a2 = lo16(p.y), a3 = hi16(p.y);
  float a4 = lo16(p.z), a5 = hi16(p.z), a6 = lo16(p.w), a7 = hi16(p.w);
#pragma unroll
  for (int j = 0; j < 6; j++) {
    uint4 g = *(const uint4*)(tab + (long)sidx[rl][j] * 256 + ch);
    a0 += lo16(g.x); a1 += hi16(g.x); a2 += lo16(g.y); a3 += hi16(g.y);
    a4 += lo16(g.z); a5 += hi16(g.z); a6 += lo16(g.w); a7 += hi16(g.w);
  }
  float4 b0 = *(const float4*)(bias + ch);
  float4 b1 = *(const float4*)(bias + ch + 4);
  a0 += b0.x; a1 += b0.y; a2 += b0.z; a3 += b0.w;
  a4 += b1.x; a5 += b1.y; a6 += b1.z; a7 += b1.w;
  if (e == 0) { a0 = a1 = a2 = a3 = a4 = a5 = a6 = a7 = 0.f; }
  else {
    a0 = fmaxf(a0, 0.f); a1 = fmaxf(a1, 0.f); a2 = fmaxf(a2, 0.f); a3 = fmaxf(a3, 0.f);
    a4 = fmaxf(a4, 0.f); a5 = fmaxf(a5, 0.f); a6 = fmaxf(a6, 0.f); a7 = fmaxf(a7, 0.f);
  }
  uint4 o; o.x = pack2(a0, a1); o.y = pack2(a2, a3); o.z = pack2(a4, a5); o.w = pack2(a6, a7);
  *(uint4*)(G + (long)(r0 + rl) * 256 + ch) = o;
}

// node gather over TB=2 steps: node[r] = relu(fo[n] + sum_j T[tl*NE+ag*em] + b_o)*vm
__global__ __launch_bounds__(256) void gather_n2_kernel(
    const u16* __restrict__ tab, const u16* __restrict__ fo,
    const int* __restrict__ agraph, const int* __restrict__ emask,
    const float* __restrict__ bias, const int* __restrict__ vmask,
    int t0, u16* __restrict__ node)
{
  int r0 = blockIdx.x * 8;
  int tl = r0 / NN;
  int n0 = r0 - tl * NN;
  const int* em_t = emask + (long)(t0 + tl) * NE;
  const int* vm_t = vmask + (long)(t0 + tl) * NN;
  __shared__ int sidx[8][6];
  __shared__ int svm[8];
  int tid = threadIdx.x;
  if (tid < 48) {
    int rr = tid / 6, j = tid - rr * 6;
    int v = agraph[(long)(n0 + rr) * 6 + j];
    sidx[rr][j] = tl * NE + v * em_t[v];
  }
  if (tid >= 48 && tid < 56) svm[tid - 48] = vm_t[n0 + (tid - 48)];
  __syncthreads();
  int rl = tid >> 5, ch = (tid & 31) * 8;
  int n = n0 + rl;
  uint4 p = *(const uint4*)(fo + (long)n * 256 + ch);
  float a0 = lo16(p.x), a1 = hi16(p.x), a2 = lo16(p.y), a3 = hi16(p.y);
  float a4 = lo16(p.z), a5 = hi16(p.z), a6 = lo16(p.w), a7 = hi16(p.w);
#pragma unroll
  for (int j = 0; j < 6; j++) {
    uint4 g = *(const uint4*)(tab + (long)sidx[rl][j] * 256 + ch);
    a0 += lo16(g.x); a1 += hi16(g.x); a2 += lo16(g.y); a3 += hi16(g.y);
    a4 += lo16(g.z); a5 += hi16(g.z); a6 += lo16(g.w); a7 += hi16(g.w);
  }
  float4 b0 = *(const float4*)(bias + ch);
  float4 b1 = *(const float4*)(bias + ch + 4);
  a0 = fmaxf(a0 + b0.x, 0.f); a1 = fmaxf(a1 + b0.y, 0.f);
  a2 = fmaxf(a2 + b0.z, 0.f); a3 = fmaxf(a3 + b0.w, 0.f);
  a4 = fmaxf(a4 + b1.x, 0.f); a5 = fmaxf(a5 + b1.y, 0.f);
  a6 = fmaxf(a6 + b1.z, 0.f); a7 = fmaxf(a7 + b1.w, 0.f);
  if (svm[rl] == 0) { a0 = a1 = a2 = a3 = a4 = a5 = a6 = a7 = 0.f; }
  uint4 o; o.x = pack2(a0, a1); o.y = pack2(a2, a3); o.z = pack2(a4, a5); o.w = pack2(a6, a7);
  *(uint4*)(node + (long)(r0 + rl) * 256 + ch) = o;
}

// zero gvec + out
__global__ __launch_bounds__(256) void init_zero_kernel(float* __restrict__ gv,
                                                        float* __restrict__ out)
{
  int i = blockIdx.x * 256 + threadIdx.x;
  gv[i] = 0.f;
  if (i == 0) out[0] = 0.f;
}

// all 9 first-layer weight transposes in one dispatch
__global__ __launch_bounds__(256) void transpose_all_kernel(
    const float* W_h, const float* U_h, const float* W_o,
    const float* tw1, const float* aw1, const float* bw1,
    const float* rw, const float* ww,
    u16* Wh_t, u16* Uh_t, u16* Wo1_t, u16* Wo2_t,
    u16* tw1_t, u16* aw1_t, u16* bw1_t, u16* rw_t, u16* ww_t)
{
  int b = blockIdx.x;
  const float* W; int K, Kpad; u16* Bt; int base;
  if      (b < 256)  { W = W_h;  K = 256; Kpad = 256; Bt = Wh_t;  base = 0; }
  else if (b < 512)  { W = U_h;  K = 256; Kpad = 256; Bt = Uh_t;  base = 256; }
  else if (b < 768)  { W = W_o;  K = 256; Kpad = 256; Bt = Wo1_t; base = 512; }
  else if (b < 1024) { W = W_o + 256 * 256; K = 256; Kpad = 256; Bt = Wo2_t; base = 768; }
  else if (b < 1568) { W = tw1;  K = 544; Kpad = 544; Bt = tw1_t; base = 1024; }
  else if (b < 2112) { W = aw1;  K = 544; Kpad = 544; Bt = aw1_t; base = 1568; }
  else if (b < 2912) { W = bw1;  K = 800; Kpad = 800; Bt = bw1_t; base = 2112; }
  else if (b < 3232) { W = rw;   K = 296; Kpad = 320; Bt = rw_t;  base = 2912; }
  else               { W = ww;   K = 260; Kpad = 288; Bt = ww_t;  base = 3232; }
  int idx = (b - base) * 256 + threadIdx.x;
  int n = idx / Kpad, k = idx - n * Kpad;
  Bt[idx] = (k < K) ? f2b(W[(long)k * 256 + n]) : (u16)0;
}

// combined: blocks [0,1876) gvec segmented-sum (2 steps); [1876,3220) head scatter
__global__ __launch_bounds__(256) void gvec_head_kernel(int t0,
    const u16* __restrict__ node, const int* __restrict__ n2g,
    float* __restrict__ gv,
    const int* __restrict__ tstep, const int* __restrict__ txid,
    const int* __restrict__ astep, const int* __restrict__ axid,
    const int* __restrict__ bstep, const int* __restrict__ bzid,
    u16* __restrict__ tv, u16* __restrict__ av, u16* __restrict__ bv,
    u16* __restrict__ wbin)
{
  int b = blockIdx.x;
  if (b < 1876) {
    int tl = (b >= 938) ? 1 : 0;
    int r0 = (b - tl * 938) * 32;
    if (r0 >= NN) return;
    int h = threadIdx.x;
    const u16* nd = node + (long)tl * NN * 256;
    float* gb = gv + (long)(t0 + tl) * BATCH * 256;
    int rend = r0 + 32; if (rend > NN) rend = NN;
    int gprev = n2g[r0];
    float acc = 0.f;
    for (int r = r0; r < rend; r++) {
      int g = n2g[r];
      if (g != gprev) { atomicAdd(gb + gprev * 256 + h, acc); acc = 0.f; gprev = g; }
      acc += b2f(nd[(long)r * 256 + h]);
    }
    atomicAdd(gb + gprev * 256 + h, acc);
    return;
  }
  int wave = threadIdx.x >> 6, lane = threadIdx.x & 63;
  int r = (b - 1876) * 4 + wave;
  int c = lane * 4;
  if (r < PT) {
    int st = tstep[r];
    if (st < t0 || st >= t0 + 2) return;
    ushort4 v = *(const ushort4*)(node + ((long)(st - t0) * NN + txid[r]) * 256 + c);
    *(ushort4*)(tv + (long)r * 544 + 256 + c) = v;
  } else if (r < PT + PA) {
    int i = r - PT;
    int st = astep[i];
    if (st < t0 || st >= t0 + 2) return;
    ushort4 v = *(const ushort4*)(node + ((long)(st - t0) * NN + axid[i]) * 256 + c);
    *(ushort4*)(av + (long)i * 544 + 256 + c) = v;
  } else if (r < PALL) {
    int i = r - PT - PA;
    int st = bstep[i];
    if (st < t0 || st >= t0 + 2) return;
    ushort4 v = *(const ushort4*)(node + ((long)(st - t0) * NN + bzid[i]) * 256 + c);
    *(ushort4*)(bv + (long)i * 800 + 512 + c) = v;
    *(ushort4*)(wbin + (long)i * 288 + c) = v;
  }
}

// fill gvec / src / one-hot segments of head inputs (after all steps)
__global__ __launch_bounds__(256) void build_static_kernel(
    const float* __restrict__ gvec, const float* __restrict__ src,
    const int* __restrict__ tstep, const int* __restrict__ tbid,
    const int* __restrict__ astep, const int* __restrict__ abid,
    const int* __restrict__ bstep, const int* __restrict__ bbid,
    const int* __restrict__ blabel, const int* __restrict__ batype,
    u16* __restrict__ tv, u16* __restrict__ av, u16* __restrict__ bv,
    u16* __restrict__ wbin, u16* __restrict__ rbin)
{
  int wave = threadIdx.x >> 6, lane = threadIdx.x & 63;
  int r = blockIdx.x * 4 + wave;
  int c = lane * 4;
  if (r < PT) {
    int st = tstep[r], bid = tbid[r];
    const float* g = gvec + ((long)st * BATCH + bid) * 256;
    u16* d = tv + (long)r * 544;
    float4 g4 = *(const float4*)(g + c);
    d[c] = f2b(g4.x); d[c + 1] = f2b(g4.y); d[c + 2] = f2b(g4.z); d[c + 3] = f2b(g4.w);
    if (lane < 8) {
      float4 s4 = *(const float4*)(src + bid * 32 + c);
      d[512 + c] = f2b(s4.x); d[512 + c + 1] = f2b(s4.y);
      d[512 + c + 2] = f2b(s4.z); d[512 + c + 3] = f2b(s4.w);
    }
  } else if (r < PT + PA) {
    int i = r - PT;
    int st = astep[i], bid = abid[i];
    const float* g = gvec + ((long)st * BATCH + bid) * 256;
    u16* d = av + (long)i * 544;
    float4 g4 = *(const float4*)(g + c);
    d[c] = f2b(g4.x); d[c + 1] = f2b(g4.y); d[c + 2] = f2b(g4.z); d[c + 3] = f2b(g4.w);
    if (lane < 8) {
      float4 s4 = *(const float4*)(src + bid * 32 + c);
      d[512 + c] = f2b(s4.x); d[512 + c + 1] = f2b(s4.y);
      d[512 + c + 2] = f2b(s4.z); d[512 + c + 3] = f2b(s4.w);
    }
  } else if (r < PALL) {
    int i = r - PT - PA;
    int st = bstep[i], bid = bbid[i];
    const float* g = gvec + ((long)st * BATCH + bid) * 256;
    u16* d = bv + (long)i * 800;
    float4 g4 = *(const float4*)(g + c);
    d[c] = f2b(g4.x); d[c + 1] = f2b(g4.y); d[c + 2] = f2b(g4.z); d[c + 3] = f2b(g4.w);
    if (lane < 8) {
      float4 s4 = *(const float4*)(src + bid * 32 + c);
      d[768 + c] = f2b(s4.x); d[768 + c + 1] = f2b(s4.y);
      d[768 + c + 2] = f2b(s4.z); d[768 + c + 3] = f2b(s4.w);
      int bl = blabel[i];
      u16* wd = wbin + (long)i * 288 + 256;
      for (int q = 0; q < 4; q++) {
        int k = c + q;
        wd[k] = f2b((k < NBOND && bl == k) ? 1.f : 0.f);
      }
    }
    if (lane < 16) {
      int at = batype[i];
      u16* rd = rbin + (long)i * 320 + 256;
      for (int q = 0; q < 4; q++) {
        int k = c + q;
        rd[k] = f2b((k < VV && at == k) ? 1.f : 0.f);
      }
    }
  }
}

// rbin[r][0:256] = sum_{j in [gs[r], r)} wb[j] * (blabel[j] > 0)
__global__ __launch_bounds__(256) void hist_kernel(
    const u16* __restrict__ wb, const int* __restrict__ gs_arr,
    const int* __restrict__ blabel, u16* __restrict__ rbin)
{
  int wave = threadIdx.x >> 6, lane = threadIdx.x & 63;
  int r = blockIdx.x * 4 + wave;
  if (r >= PB) return;
  int c = lane * 4;
  float a0 = 0.f, a1 = 0.f, a2 = 0.f, a3 = 0.f;
  int gs = gs_arr[r];
  for (int j = gs; j < r; j++) {
    if (blabel[j] > 0) {
      ushort4 g = *(const ushort4*)(wb + (long)j * 256 + c);
      a0 += b2f(g.x); a1 += b2f(g.y); a2 += b2f(g.z); a3 += b2f(g.w);
    }
  }
  u16* rd = rbin + (long)r * 320;
  rd[c] = f2b(a0); rd[c + 1] = f2b(a1); rd[c + 2] = f2b(a2); rd[c + 3] = f2b(a3);
}

// ---------------------------------------------------------------------------
extern "C" void kernel_launch(void* const* d_in, const int* in_sizes, int n_in,
                              void* d_out, int out_size, void* d_ws, size_t ws_size,
                              hipStream_t stream)
{
  const float* src      = (const float*)d_in[0];
  const float* fnode    = (const float*)d_in[1];
  const float* fmess    = (const float*)d_in[2];
  const float* W_h      = (const float*)d_in[3];
  const float* U_h      = (const float*)d_in[4];
  const float* b_h      = (const float*)d_in[5];
  const float* W_o      = (const float*)d_in[6];
  const float* b_o      = (const float*)d_in[7];
  const float* topo_w1  = (const float*)d_in[8];
  const float* topo_b1  = (const float*)d_in[9];
  const float* topo_w2  = (const float*)d_in[10];
  const float* topo_b2  = (const float*)d_in[11];
  const float* atom_w1  = (const float*)d_in[12];
  const float* atom_b1  = (const float*)d_in[13];
  const float* atom_w2  = (const float*)d_in[14];
  const float* atom_b2  = (const float*)d_in[15];
  const float* bond_w1  = (const float*)d_in[16];
  const float* bond_b1  = (const float*)d_in[17];
  const float* bond_w2  = (const float*)d_in[18];
  const float* bond_b2  = (const float*)d_in[19];
  const float* rbond_w  = (const float*)d_in[20];
  const float* rbond_b  = (const float*)d_in[21];
  const float* wbond_w  = (const float*)d_in[22];
  const float* wbond_b  = (const float*)d_in[23];
  const int* agraph     = (const int*)d_in[24];
  const int* bgraph     = (const int*)d_in[25];
  const int* node2graph = (const int*)d_in[26];
  const int* emask      = (const int*)d_in[27];
  const int* vmask      = (const int*)d_in[28];
  const int* topo_step  = (const int*)d_in[29];
  const int* topo_bid   = (const int*)d_in[30];
  const int* topo_xid   = (const int*)d_in[31];
  const int* topo_label = (const int*)d_in[32];
  const int* atom_step  = (const int*)d_in[33];
  const int* atom_bid   = (const int*)d_in[34];
  const int* atom_xid   = (const int*)d_in[35];
  const int* atom_label = (const int*)d_in[36];
  const int* bond_step  = (const int*)d_in[37];
  const int* bond_bid   = (const int*)d_in[38];
  const int* bond_zid   = (const int*)d_in[39];
  const int* bond_atype = (const int*)d_in[40];
  const int* bond_label = (const int*)d_in[41];
  const int* bond_gs    = (const int*)d_in[42];

  char* wp = (char*)d_ws;
  auto alloc = [&](size_t bytes) -> char* {
    char* p = wp; wp += (bytes + 255) & ~(size_t)255; return p;
  };
  // fixed (~95 MB) + chunked (2x61 MB) = ~217 MB < 256 MB L3
  u16* preB    = (u16*)alloc((size_t)NE * 256 * 2);
  u16* hu1B    = (u16*)alloc((size_t)NE * 256 * 2);
  u16* foB     = (u16*)alloc((size_t)NN * 256 * 2);
  float* gvec  = (float*)alloc((size_t)TT * BATCH * 256 * 4);
  u16* Wh_t    = (u16*)alloc(256 * 256 * 2);
  u16* Uh_t    = (u16*)alloc(256 * 256 * 2);
  u16* Wo1_t   = (u16*)alloc(256 * 256 * 2);
  u16* Wo2_t   = (u16*)alloc(256 * 256 * 2);
  u16* tw1_t   = (u16*)alloc(256 * 544 * 2);
  u16* aw1_t   = (u16*)alloc(256 * 544 * 2);
  u16* bw1_t   = (u16*)alloc(256 * 800 * 2);
  u16* rw_t    = (u16*)alloc(256 * 320 * 2);
  u16* ww_t    = (u16*)alloc(256 * 288 * 2);
  u16* w2c     = (u16*)alloc(3 * 64 * 256 * 2);
  float* b2c   = (float*)alloc(192 * 4);
  u16* tva     = (u16*)alloc((size_t)(PT + PA) * 544 * 2);
  u16* bv      = (u16*)alloc((size_t)PB * 800 * 2);
  u16* wbin    = (u16*)alloc((size_t)PB * 288 * 2);
  u16* rbin    = (u16*)alloc((size_t)PB * 320 * 2);
  u16* wb      = (u16*)alloc((size_t)PB * 256 * 2);
  u16* hid_all = (u16*)alloc((size_t)PALL * 256 * 2);
  float* logitsL = (float*)alloc((size_t)PALL * 64 * 4);
  u16* G       = (u16*)alloc((size_t)2 * NE * 256 * 2);
  u16* T       = (u16*)alloc((size_t)2 * NE * 256 * 2);
  u16* tv      = tva;
  u16* av      = tva + (size_t)PT * 544;
  u16* nodeB   = G;   // alias: G free when gather_n2 runs

  float* out = (float*)d_out;

  init_zero_kernel<<<1536, 256, 0, stream>>>(gvec, out);
  transpose_all_kernel<<<3520, 256, 0, stream>>>(W_h, U_h, W_o, topo_w1, atom_w1, bond_w1,
      rbond_w, wbond_w, Wh_t, Uh_t, Wo1_t, Wo2_t, tw1_t, aw1_t, bw1_t, rw_t, ww_t);
  build_w2c_kernel<<<192, 256, 0, stream>>>(topo_w2, topo_b2, atom_w2, atom_b2,
                                            bond_w2, bond_b2, w2c, b2c);

  // step-invariant precomputes
  gemm_n256_kernel<1><<<(NE + 127) / 128, 512, 0, stream>>>(fmess, NE, Wh_t, preB, nullptr);
  gemm_n256_kernel<1><<<(NN + 127) / 128, 512, 0, stream>>>(fnode, NN, Wo1_t, foB, nullptr);
  gemm_n256_kernel<2><<<(NE + 127) / 128, 512, 0, stream>>>(preB, NE, Uh_t, hu1B, b_h);

  for (int t0 = 0; t0 < TT; t0 += 2) {
    int M2 = 2 * NE;
    int gb = 2 * NE / 8;
    int mb = (M2 + 127) / 128;
    gather_e2_kernel<1><<<gb, 256, 0, stream>>>(hu1B, preB, bgraph, emask, b_h, t0, G);
    gemm_n256_kernel<0><<<mb, 512, 0, stream>>>(G, M2, Uh_t, T, nullptr);
    gather_e2_kernel<0><<<gb, 256, 0, stream>>>(T, preB, bgraph, emask, b_h, t0, G);
    gemm_n256_kernel<0><<<mb, 512, 0, stream>>>(G, M2, Uh_t, T, nullptr);
    gather_e2_kernel<0><<<gb, 256, 0, stream>>>(T, preB, bgraph, emask, b_h, t0, G);
    gemm_n256_kernel<0><<<mb, 512, 0, stream>>>(G, M2, Wo2_t, T, nullptr);
    gather_n2_kernel<<<2 * NN / 8, 256, 0, stream>>>(T, foB, agraph, emask, b_o,
                                                     vmask, t0, nodeB);
    gvec_head_kernel<<<3220, 256, 0, stream>>>(t0, nodeB, node2graph, gvec,
        topo_step, topo_xid, atom_step, atom_xid, bond_step, bond_zid,
        tv, av, bv, wbin);
  }

  // static head-input segments
  build_static_kernel<<<1344, 256, 0, stream>>>(gvec, src,
      topo_step, topo_bid, atom_step, atom_bid, bond_step, bond_bid,
      bond_label, bond_atype, tv, av, bv, wbin, rbin);

  // heads -> hid_all
  gemm_ta_kernel<<<dim3((PT + PA) / 128, 2), 256, 0, stream>>>(tva, tw1_t, aw1_t,
                                                               topo_b1, atom_b1, hid_all);
  gemm_bt_kernel<1><<<dim3(20, 2), 256, 0, stream>>>(wbin, 288, PB, ww_t, 288,
                                                     wb, 256, wbond_b);
  hist_kernel<<<640, 256, 0, stream>>>(wb, bond_gs, bond_label, rbin);
  gemm_bt_kernel<1><<<dim3(20, 2), 256, 0, stream>>>(rbin, 320, PB, rw_t, 320,
                                                     bv + 256, 800, rbond_b);
  gemm_bt_kernel<1><<<dim3(20, 2), 256, 0, stream>>>(bv, 800, PB, bw1_t, 800,
                                                     hid_all + (size_t)(PT + PA) * 256,
                                                     256, bond_b1);

  // losses: logits GEMM + finalize
  gemm_logits_kernel<<<PALL / 128, 256, 0, stream>>>(hid_all, w2c, b2c, logitsL);
  loss_finalize_kernel<<<PALL / 4, 256, 0, stream>>>(logitsL, topo_label, atom_label,
                                                     bond_label, out);
}

// Round 7
// 973.919 us; speedup vs baseline: 1.8114x; 1.1706x over previous
//
#include <hip/hip_runtime.h>
#include <cstdint>
#include <cstddef>

using short8  = __attribute__((ext_vector_type(8))) short;
using floatx4 = __attribute__((ext_vector_type(4))) float;
using floatx2 = __attribute__((ext_vector_type(2))) float;
typedef unsigned short u16;
typedef unsigned char  u8;

constexpr int NN = 30000;   // nodes
constexpr int NE = 60000;   // edges / messages
constexpr int BATCH = 256;
constexpr int VV = 40;
constexpr int NBOND = 4;
constexpr int TT = 6;
constexpr int PT = 1536, PA = 1280, PB = 2560;
constexpr int PALL = PT + PA + PB;   // 5376

__device__ __forceinline__ float b2f(u16 h) {
  union { unsigned u; float f; } v; v.u = ((unsigned)h) << 16; return v.f;
}
__device__ __forceinline__ u16 f2b(float f) {
  union { float f; unsigned u; } v; v.f = f;
  unsigned r = v.u + 0x7FFFu + ((v.u >> 16) & 1u);
  return (u16)(r >> 16);
}
__device__ __forceinline__ float lo16(unsigned u) {
  union { unsigned x; float f; } v; v.x = u << 16; return v.f;
}
__device__ __forceinline__ float hi16(unsigned u) {
  union { unsigned x; float f; } v; v.x = u & 0xffff0000u; return v.f;
}
__device__ __forceinline__ unsigned pack2(float a, float b) {
  return ((unsigned)f2b(a)) | (((unsigned)f2b(b)) << 16);
}
// fp8 e4m3 (gfx950 OCP) HW conversions — used round-trip internally only
__device__ __forceinline__ floatx2 f8lo(unsigned v) {
  return __builtin_amdgcn_cvt_pk_f32_fp8((int)v, false);
}
__device__ __forceinline__ floatx2 f8hi(unsigned v) {
  return __builtin_amdgcn_cvt_pk_f32_fp8((int)v, true);
}
__device__ __forceinline__ unsigned pk8(float a, float b, float c, float d) {
  int w = __builtin_amdgcn_cvt_pk_fp8_f32(a, b, 0, false);
  w = __builtin_amdgcn_cvt_pk_fp8_f32(c, d, w, true);
  return (unsigned)w;
}
__device__ __forceinline__ u8 f2f8(float v) {
  return (u8)(__builtin_amdgcn_cvt_pk_fp8_f32(v, v, 0, false) & 0xff);
}

// ---------------------------------------------------------------------------
// Full-N GEMM: C[M,256] = A[M,256] @ B[256,256], 128x256 tile, 512 threads.
// AMODE 1: A f32 (convert in staging)
// AMODE 2: A fp8; staged = relu(A + abias[kcol]); row 0 -> 0   (h1 fold)
// AMODE 3: A fp8 plain
// OMODE 0: C bf16   OMODE 1: C fp8
// Bt = B^T row-major bf16 [256][256]. MFMA runs bf16.
// ---------------------------------------------------------------------------
template<int AMODE, int OMODE>
__global__ __launch_bounds__(512) void gemm_n256_kernel(
    const void* __restrict__ Av, int M,
    const u16* __restrict__ Bt,
    void* __restrict__ Cv, const float* __restrict__ abias)
{
  __shared__ __align__(16) u16 As[128][40];
  __shared__ __align__(16) u16 Bs[256][40];
  const int tid = threadIdx.x;
  const int rowbase = blockIdx.x * 128;
  const int wave = tid >> 6, lane = tid & 63;
  const int wm = wave >> 2, wn = wave & 3;
  const int lr = lane & 15, lk = (lane >> 4) * 8;
  const int arow = tid >> 2, ac8 = (tid & 3) * 8;
  const int brow = tid >> 1, bc16 = (tid & 1) * 16;

  floatx4 acc[4][4];
#pragma unroll
  for (int i = 0; i < 4; i++)
#pragma unroll
    for (int j = 0; j < 4; j++) acc[i][j] = {0.f, 0.f, 0.f, 0.f};

  for (int k0 = 0; k0 < 256; k0 += 32) {
    {
      int grow = rowbase + arow;
      uint4 av = {0u, 0u, 0u, 0u};
      if (AMODE == 1) {
        if (grow < M) {
          const float* Af = (const float*)Av;
          float4 f0 = *(const float4*)(Af + (long)grow * 256 + k0 + ac8);
          float4 f1 = *(const float4*)(Af + (long)grow * 256 + k0 + ac8 + 4);
          av.x = pack2(f0.x, f0.y); av.y = pack2(f0.z, f0.w);
          av.z = pack2(f1.x, f1.y); av.w = pack2(f1.z, f1.w);
        }
      } else {
        if (grow < M) {
          const u8* Af8 = (const u8*)Av;
          uint2 v8 = *(const uint2*)(Af8 + (long)grow * 256 + k0 + ac8);
          floatx2 f0 = f8lo(v8.x), f1 = f8hi(v8.x), f2 = f8lo(v8.y), f3 = f8hi(v8.y);
          float a0 = f0.x, a1 = f0.y, a2 = f1.x, a3 = f1.y;
          float a4 = f2.x, a5 = f2.y, a6 = f3.x, a7 = f3.y;
          if (AMODE == 2) {
            if (grow == 0) { a0 = a1 = a2 = a3 = a4 = a5 = a6 = a7 = 0.f; }
            else {
              float4 b0 = *(const float4*)(abias + k0 + ac8);
              float4 b1 = *(const float4*)(abias + k0 + ac8 + 4);
              a0 = fmaxf(a0 + b0.x, 0.f); a1 = fmaxf(a1 + b0.y, 0.f);
              a2 = fmaxf(a2 + b0.z, 0.f); a3 = fmaxf(a3 + b0.w, 0.f);
              a4 = fmaxf(a4 + b1.x, 0.f); a5 = fmaxf(a5 + b1.y, 0.f);
              a6 = fmaxf(a6 + b1.z, 0.f); a7 = fmaxf(a7 + b1.w, 0.f);
            }
          }
          av.x = pack2(a0, a1); av.y = pack2(a2, a3);
          av.z = pack2(a4, a5); av.w = pack2(a6, a7);
        }
      }
      *(uint4*)(&As[arow][ac8]) = av;
      uint4 v0 = *(const uint4*)(Bt + (long)brow * 256 + k0 + bc16);
      uint4 v1 = *(const uint4*)(Bt + (long)brow * 256 + k0 + bc16 + 8);
      *(uint4*)(&Bs[brow][bc16]) = v0;
      *(uint4*)(&Bs[brow][bc16 + 8]) = v1;
    }
    __syncthreads();
    short8 af[4], bf[4];
#pragma unroll
    for (int mt = 0; mt < 4; mt++) af[mt] = *(const short8*)(&As[wm * 64 + mt * 16 + lr][lk]);
#pragma unroll
    for (int nt = 0; nt < 4; nt++) bf[nt] = *(const short8*)(&Bs[wn * 64 + nt * 16 + lr][lk]);
#pragma unroll
    for (int mt = 0; mt < 4; mt++)
#pragma unroll
      for (int nt = 0; nt < 4; nt++)
        acc[mt][nt] = __builtin_amdgcn_mfma_f32_16x16x32_bf16(af[mt], bf[nt], acc[mt][nt], 0, 0, 0);
    __syncthreads();
  }

  const int rq = (lane >> 4) * 4;
#pragma unroll
  for (int mt = 0; mt < 4; mt++) {
#pragma unroll
    for (int nt = 0; nt < 4; nt++) {
      int gcol = wn * 64 + nt * 16 + lr;
#pragma unroll
      for (int r2 = 0; r2 < 4; r2++) {
        int grow = rowbase + wm * 64 + mt * 16 + rq + r2;
        if (grow < M) {
          float v = acc[mt][nt][r2];
          if (OMODE == 0) ((u16*)Cv)[(long)grow * 256 + gcol] = f2b(v);
          else            ((u8*)Cv)[(long)grow * 256 + gcol] = f2f8(v);
        }
      }
    }
  }
}

// ---------------------------------------------------------------------------
// 128x128-tile GEMM for the head matrices. MODE 0: plain  MODE 1: relu+bias
// ---------------------------------------------------------------------------
template<int MODE>
__global__ __launch_bounds__(256) void gemm_bt_kernel(
    const u16* __restrict__ A, int lda, int M,
    const u16* __restrict__ Bt, int K,
    u16* __restrict__ C, int ldc, const float* __restrict__ bias)
{
  __shared__ __align__(16) u16 As[128][56];
  __shared__ __align__(16) u16 Bs[128][56];
  const int tid  = threadIdx.x;
  const int wave = tid >> 6, lane = tid & 63;
  const int wm = wave >> 1, wn = wave & 1;
  const int lr = lane & 15, lk = (lane >> 4) * 8;
  const int rowbase = blockIdx.x * 128;
  const int colbase = blockIdx.y * 128;

  floatx4 acc[4][4];
#pragma unroll
  for (int i = 0; i < 4; i++)
#pragma unroll
    for (int j = 0; j < 4; j++) acc[i][j] = {0.f, 0.f, 0.f, 0.f};

  for (int k0 = 0; k0 < K; k0 += 32) {
#pragma unroll
    for (int r = 0; r < 2; r++) {
      int c = tid + 256 * r;
      int row = c >> 2, cc = (c & 3) * 8;
      int grow = rowbase + row;
      uint4 av = {0u, 0u, 0u, 0u};
      if (grow < M) av = *(const uint4*)(A + (long)grow * lda + k0 + cc);
      *(uint4*)(&As[row][cc]) = av;
      uint4 bv = *(const uint4*)(Bt + (long)(colbase + row) * K + k0 + cc);
      *(uint4*)(&Bs[row][cc]) = bv;
    }
    __syncthreads();
    short8 af[4], bf[4];
#pragma unroll
    for (int mt = 0; mt < 4; mt++) af[mt] = *(const short8*)(&As[wm * 64 + mt * 16 + lr][lk]);
#pragma unroll
    for (int nt = 0; nt < 4; nt++) bf[nt] = *(const short8*)(&Bs[wn * 64 + nt * 16 + lr][lk]);
#pragma unroll
    for (int mt = 0; mt < 4; mt++)
#pragma unroll
      for (int nt = 0; nt < 4; nt++)
        acc[mt][nt] = __builtin_amdgcn_mfma_f32_16x16x32_bf16(af[mt], bf[nt], acc[mt][nt], 0, 0, 0);
    __syncthreads();
  }

  const int rq = (lane >> 4) * 4;
#pragma unroll
  for (int mt = 0; mt < 4; mt++) {
#pragma unroll
    for (int nt = 0; nt < 4; nt++) {
      int gcol = colbase + wn * 64 + nt * 16 + lr;
#pragma unroll
      for (int r2 = 0; r2 < 4; r2++) {
        int grow = rowbase + wm * 64 + mt * 16 + rq + r2;
        if (grow < M) {
          float v = acc[mt][nt][r2];
          if (MODE == 1) { v += bias[gcol]; v = v > 0.f ? v : 0.f; }
          C[(long)grow * ldc + gcol] = f2b(v);
        }
      }
    }
  }
}

// Merged topo+atom head GEMM (K=544): rowbase<PT -> (Bt1,b1) else (Bt2,b2)
__global__ __launch_bounds__(256) void gemm_ta_kernel(
    const u16* __restrict__ A,
    const u16* __restrict__ Bt1, const u16* __restrict__ Bt2,
    const float* __restrict__ b1, const float* __restrict__ b2,
    u16* __restrict__ C)
{
  constexpr int K = 544;
  __shared__ __align__(16) u16 As[128][56];
  __shared__ __align__(16) u16 Bs[128][56];
  const int tid  = threadIdx.x;
  const int wave = tid >> 6, lane = tid & 63;
  const int wm = wave >> 1, wn = wave & 1;
  const int lr = lane & 15, lk = (lane >> 4) * 8;
  const int rowbase = blockIdx.x * 128;
  const int colbase = blockIdx.y * 128;
  const u16* Bt = (rowbase < PT) ? Bt1 : Bt2;
  const float* bias = (rowbase < PT) ? b1 : b2;

  floatx4 acc[4][4];
#pragma unroll
  for (int i = 0; i < 4; i++)
#pragma unroll
    for (int j = 0; j < 4; j++) acc[i][j] = {0.f, 0.f, 0.f, 0.f};

  for (int k0 = 0; k0 < K; k0 += 32) {
#pragma unroll
    for (int r = 0; r < 2; r++) {
      int c = tid + 256 * r;
      int row = c >> 2, cc = (c & 3) * 8;
      int grow = rowbase + row;
      uint4 av = *(const uint4*)(A + (long)grow * K + k0 + cc);
      *(uint4*)(&As[row][cc]) = av;
      uint4 bv = *(const uint4*)(Bt + (long)(colbase + row) * K + k0 + cc);
      *(uint4*)(&Bs[row][cc]) = bv;
    }
    __syncthreads();
    short8 af[4], bf[4];
#pragma unroll
    for (int mt = 0; mt < 4; mt++) af[mt] = *(const short8*)(&As[wm * 64 + mt * 16 + lr][lk]);
#pragma unroll
    for (int nt = 0; nt < 4; nt++) bf[nt] = *(const short8*)(&Bs[wn * 64 + nt * 16 + lr][lk]);
#pragma unroll
    for (int mt = 0; mt < 4; mt++)
#pragma unroll
      for (int nt = 0; nt < 4; nt++)
        acc[mt][nt] = __builtin_amdgcn_mfma_f32_16x16x32_bf16(af[mt], bf[nt], acc[mt][nt], 0, 0, 0);
    __syncthreads();
  }

  const int rq = (lane >> 4) * 4;
#pragma unroll
  for (int mt = 0; mt < 4; mt++) {
#pragma unroll
    for (int nt = 0; nt < 4; nt++) {
      int gcol = colbase + wn * 64 + nt * 16 + lr;
#pragma unroll
      for (int r2 = 0; r2 < 4; r2++) {
        int grow = rowbase + wm * 64 + mt * 16 + rq + r2;
        float v = acc[mt][nt][r2] + bias[gcol];
        v = v > 0.f ? v : 0.f;
        C[(long)grow * 256 + gcol] = f2b(v);
      }
    }
  }
}

// ---------------------------------------------------------------------------
// Logits GEMM: L[5376,64] = hid_all @ w2c[seg] + b2c[seg]   (f32 out)
// ---------------------------------------------------------------------------
__global__ __launch_bounds__(256) void gemm_logits_kernel(
    const u16* __restrict__ A, const u16* __restrict__ w2c,
    const float* __restrict__ b2c, float* __restrict__ L)
{
  __shared__ __align__(16) u16 As[128][40];
  __shared__ __align__(16) u16 Bs[64][40];
  const int tid = threadIdx.x;
  const int rowbase = blockIdx.x * 128;
  const int seg = (rowbase < PT) ? 0 : (rowbase < PT + PA ? 1 : 2);
  const u16* Bt = w2c + seg * 64 * 256;
  const int wave = tid >> 6, lane = tid & 63;
  const int wm = wave >> 1, wn = wave & 1;
  const int lr = lane & 15, lk = (lane >> 4) * 8;
  const int sr = tid >> 2, sc = (tid & 3) * 8;

  floatx4 acc[4][2];
#pragma unroll
  for (int i = 0; i < 4; i++)
#pragma unroll
    for (int j = 0; j < 2; j++) acc[i][j] = {0.f, 0.f, 0.f, 0.f};

  for (int k0 = 0; k0 < 256; k0 += 32) {
    *(uint4*)(&As[sr][sc]) = *(const uint4*)(A + (long)(rowbase + sr) * 256 + k0 + sc);
    *(uint4*)(&As[sr + 64][sc]) = *(const uint4*)(A + (long)(rowbase + sr + 64) * 256 + k0 + sc);
    *(uint4*)(&Bs[sr][sc]) = *(const uint4*)(Bt + (long)sr * 256 + k0 + sc);
    __syncthreads();
    short8 af[4], bf[2];
#pragma unroll
    for (int mt = 0; mt < 4; mt++) af[mt] = *(const short8*)(&As[wm * 64 + mt * 16 + lr][lk]);
#pragma unroll
    for (int nt = 0; nt < 2; nt++) bf[nt] = *(const short8*)(&Bs[wn * 32 + nt * 16 + lr][lk]);
#pragma unroll
    for (int mt = 0; mt < 4; mt++)
#pragma unroll
      for (int nt = 0; nt < 2; nt++)
        acc[mt][nt] = __builtin_amdgcn_mfma_f32_16x16x32_bf16(af[mt], bf[nt], acc[mt][nt], 0, 0, 0);
    __syncthreads();
  }

  const int rq = (lane >> 4) * 4;
#pragma unroll
  for (int mt = 0; mt < 4; mt++) {
#pragma unroll
    for (int nt = 0; nt < 2; nt++) {
      int gcol = wn * 32 + nt * 16 + lr;
#pragma unroll
      for (int r2 = 0; r2 < 4; r2++) {
        int grow = rowbase + wm * 64 + mt * 16 + rq + r2;
        L[(long)grow * 64 + gcol] = acc[mt][nt][r2] + b2c[seg * 64 + gcol];
      }
    }
  }
}

// build combined second-layer weights (bf16, Bt layout) + biases
__global__ __launch_bounds__(256) void build_w2c_kernel(
    const float* __restrict__ tw2, const float* __restrict__ tb2,
    const float* __restrict__ aw2, const float* __restrict__ ab2,
    const float* __restrict__ bw2, const float* __restrict__ bb2,
    u16* __restrict__ w2c, float* __restrict__ b2c)
{
  int idx = blockIdx.x * 256 + threadIdx.x;           // [0, 3*64*256)
  int seg = idx / 16384;
  int rem = idx - seg * 16384;
  int n = rem >> 8, k = rem & 255;
  const float* W; int NC;
  if (seg == 0)      { W = tw2; NC = 1; }
  else if (seg == 1) { W = aw2; NC = VV; }
  else               { W = bw2; NC = NBOND; }
  w2c[idx] = (n < NC) ? f2b(W[(long)k * NC + n]) : (u16)0;
  if (idx < 192) {
    int s2 = idx / 64, n2 = idx & 63;
    const float* B2 = (s2 == 0) ? tb2 : (s2 == 1 ? ab2 : bb2);
    int NC2 = (s2 == 0) ? 1 : (s2 == 1 ? VV : NBOND);
    b2c[idx] = (n2 < NC2) ? B2[n2] : 0.f;
  }
}

// final loss from logits: 1344 blocks x 4 rows; one atomic per block
__global__ __launch_bounds__(256) void loss_finalize_kernel(
    const float* __restrict__ L,
    const int* __restrict__ tlab, const int* __restrict__ alab,
    const int* __restrict__ blab, float* __restrict__ out)
{
  __shared__ float part[4];
  int wave = threadIdx.x >> 6, lane = threadIdx.x & 63;
  int r = blockIdx.x * 4 + wave;
  float contrib = 0.f;
  if (r < PT) {
    float l = L[(long)r * 64];
    float y = (float)tlab[r];
    contrib = fmaxf(l, 0.f) + log1pf(expf(-fabsf(l))) - l * y;
  } else {
    int NC, lb;
    if (r < PT + PA) { NC = VV; lb = alab[r - PT]; }
    else             { NC = NBOND; lb = blab[r - PT - PA]; }
    bool valid = lane < NC;
    float logit = valid ? L[(long)r * 64 + lane] : -1e30f;
    float m = logit;
#pragma unroll
    for (int off = 32; off > 0; off >>= 1) m = fmaxf(m, __shfl_xor(m, off));
    float e = valid ? expf(logit - m) : 0.f;
#pragma unroll
    for (int off = 32; off > 0; off >>= 1) e += __shfl_xor(e, off);
    float lse = m + logf(e);
    float ll = __shfl(logit, lb);
    contrib = lse - ll;
  }
  if (lane == 0) part[wave] = contrib;
  __syncthreads();
  if (threadIdx.x == 0)
    atomicAdd(out, (part[0] + part[1] + part[2] + part[3]) * (1.0f / BATCH));
}

// ---------------------------------------------------------------------------
// TB=2 fp8 gathers: 8 rows/block, 32 threads/row, 8B (8 fp8)/thread.
// SHARED_TAB=1: tab step-invariant (hu1B); 0: tab = T chunk (row tl*NE + idx)
// G[r] = relu(pre[e] + sum_j tab[idx] + bias) * (e>0)   — all fp8 in/out
// ---------------------------------------------------------------------------
template<int SHARED_TAB>
__global__ __launch_bounds__(256) void gather_e2_kernel(
    const u8* __restrict__ tab, const u8* __restrict__ pre,
    const int* __restrict__ bgraph, const int* __restrict__ emask,
    const float* __restrict__ bias, int t0, u8* __restrict__ G)
{
  int r0 = blockIdx.x * 8;
  int tl = r0 / NE;
  int e0 = r0 - tl * NE;
  const int* em_t = emask + (long)(t0 + tl) * NE;
  __shared__ int sidx[8][6];
  int tid = threadIdx.x;
  if (tid < 48) {
    int rr = tid / 6, j = tid - rr * 6;
    int v = bgraph[(long)(e0 + rr) * 6 + j];
    v = v * em_t[v];
    sidx[rr][j] = SHARED_TAB ? v : (tl * NE + v);
  }
  __syncthreads();
  int rl = tid >> 5, ch = (tid & 31) * 8;
  int e = e0 + rl;
  uint2 p = *(const uint2*)(pre + (long)e * 256 + ch);
  floatx2 p0 = f8lo(p.x), p1 = f8hi(p.x), p2 = f8lo(p.y), p3 = f8hi(p.y);
  float a0 = p0.x, a1 = p0.y, a2 = p1.x, a3 = p1.y;
  float a4 = p2.x, a5 = p2.y, a6 = p3.x, a7 = p3.y;
#pragma unroll
  for (int j = 0; j < 6; j++) {
    uint2 g = *(const uint2*)(tab + (long)sidx[rl][j] * 256 + ch);
    floatx2 g0 = f8lo(g.x), g1 = f8hi(g.x), g2 = f8lo(g.y), g3 = f8hi(g.y);
    a0 += g0.x; a1 += g0.y; a2 += g1.x; a3 += g1.y;
    a4 += g2.x; a5 += g2.y; a6 += g3.x; a7 += g3.y;
  }
  float4 b0 = *(const float4*)(bias + ch);
  float4 b1 = *(const float4*)(bias + ch + 4);
  a0 += b0.x; a1 += b0.y; a2 += b0.z; a3 += b0.w;
  a4 += b1.x; a5 += b1.y; a6 += b1.z; a7 += b1.w;
  if (e == 0) { a0 = a1 = a2 = a3 = a4 = a5 = a6 = a7 = 0.f; }
  else {
    a0 = fmaxf(a0, 0.f); a1 = fmaxf(a1, 0.f); a2 = fmaxf(a2, 0.f); a3 = fmaxf(a3, 0.f);
    a4 = fmaxf(a4, 0.f); a5 = fmaxf(a5, 0.f); a6 = fmaxf(a6, 0.f); a7 = fmaxf(a7, 0.f);
  }
  uint2 o; o.x = pk8(a0, a1, a2, a3); o.y = pk8(a4, a5, a6, a7);
  *(uint2*)(G + (long)(r0 + rl) * 256 + ch) = o;
}

// node gather: node[r](bf16) = relu(fo[n](bf16) + sum_j T[tl*NE+ag*em](fp8) + b_o)*vm
__global__ __launch_bounds__(256) void gather_n2_kernel(
    const u8* __restrict__ tab, const u16* __restrict__ fo,
    const int* __restrict__ agraph, const int* __restrict__ emask,
    const float* __restrict__ bias, const int* __restrict__ vmask,
    int t0, u16* __restrict__ node)
{
  int r0 = blockIdx.x * 8;
  int tl = r0 / NN;
  int n0 = r0 - tl * NN;
  const int* em_t = emask + (long)(t0 + tl) * NE;
  const int* vm_t = vmask + (long)(t0 + tl) * NN;
  __shared__ int sidx[8][6];
  __shared__ int svm[8];
  int tid = threadIdx.x;
  if (tid < 48) {
    int rr = tid / 6, j = tid - rr * 6;
    int v = agraph[(long)(n0 + rr) * 6 + j];
    sidx[rr][j] = tl * NE + v * em_t[v];
  }
  if (tid >= 48 && tid < 56) svm[tid - 48] = vm_t[n0 + (tid - 48)];
  __syncthreads();
  int rl = tid >> 5, ch = (tid & 31) * 8;
  int n = n0 + rl;
  uint4 p = *(const uint4*)(fo + (long)n * 256 + ch);
  float a0 = lo16(p.x), a1 = hi16(p.x), a2 = lo16(p.y), a3 = hi16(p.y);
  float a4 = lo16(p.z), a5 = hi16(p.z), a6 = lo16(p.w), a7 = hi16(p.w);
#pragma unroll
  for (int j = 0; j < 6; j++) {
    uint2 g = *(const uint2*)(tab + (long)sidx[rl][j] * 256 + ch);
    floatx2 g0 = f8lo(g.x), g1 = f8hi(g.x), g2 = f8lo(g.y), g3 = f8hi(g.y);
    a0 += g0.x; a1 += g0.y; a2 += g1.x; a3 += g1.y;
    a4 += g2.x; a5 += g2.y; a6 += g3.x; a7 += g3.y;
  }
  float4 b0 = *(const float4*)(bias + ch);
  float4 b1 = *(const float4*)(bias + ch + 4);
  a0 = fmaxf(a0 + b0.x, 0.f); a1 = fmaxf(a1 + b0.y, 0.f);
  a2 = fmaxf(a2 + b0.z, 0.f); a3 = fmaxf(a3 + b0.w, 0.f);
  a4 = fmaxf(a4 + b1.x, 0.f); a5 = fmaxf(a5 + b1.y, 0.f);
  a6 = fmaxf(a6 + b1.z, 0.f); a7 = fmaxf(a7 + b1.w, 0.f);
  if (svm[rl] == 0) { a0 = a1 = a2 = a3 = a4 = a5 = a6 = a7 = 0.f; }
  uint4 o; o.x = pack2(a0, a1); o.y = pack2(a2, a3); o.z = pack2(a4, a5); o.w = pack2(a6, a7);
  *(uint4*)(node + (long)(r0 + rl) * 256 + ch) = o;
}

// zero gvec + out
__global__ __launch_bounds__(256) void init_zero_kernel(float* __restrict__ gv,
                                                        float* __restrict__ out)
{
  int i = blockIdx.x * 256 + threadIdx.x;
  gv[i] = 0.f;
  if (i == 0) out[0] = 0.f;
}

// all 9 first-layer weight transposes in one dispatch
__global__ __launch_bounds__(256) void transpose_all_kernel(
    const float* W_h, const float* U_h, const float* W_o,
    const float* tw1, const float* aw1, const float* bw1,
    const float* rw, const float* ww,
    u16* Wh_t, u16* Uh_t, u16* Wo1_t, u16* Wo2_t,
    u16* tw1_t, u16* aw1_t, u16* bw1_t, u16* rw_t, u16* ww_t)
{
  int b = blockIdx.x;
  const float* W; int K, Kpad; u16* Bt; int base;
  if      (b < 256)  { W = W_h;  K = 256; Kpad = 256; Bt = Wh_t;  base = 0; }
  else if (b < 512)  { W = U_h;  K = 256; Kpad = 256; Bt = Uh_t;  base = 256; }
  else if (b < 768)  { W = W_o;  K = 256; Kpad = 256; Bt = Wo1_t; base = 512; }
  else if (b < 1024) { W = W_o + 256 * 256; K = 256; Kpad = 256; Bt = Wo2_t; base = 768; }
  else if (b < 1568) { W = tw1;  K = 544; Kpad = 544; Bt = tw1_t; base = 1024; }
  else if (b < 2112) { W = aw1;  K = 544; Kpad = 544; Bt = aw1_t; base = 1568; }
  else if (b < 2912) { W = bw1;  K = 800; Kpad = 800; Bt = bw1_t; base = 2112; }
  else if (b < 3232) { W = rw;   K = 296; Kpad = 320; Bt = rw_t;  base = 2912; }
  else               { W = ww;   K = 260; Kpad = 288; Bt = ww_t;  base = 3232; }
  int idx = (b - base) * 256 + threadIdx.x;
  int n = idx / Kpad, k = idx - n * Kpad;
  Bt[idx] = (k < K) ? f2b(W[(long)k * 256 + n]) : (u16)0;
}

// combined: blocks [0,1876) gvec segmented-sum (2 steps); [1876,3220) head scatter
__global__ __launch_bounds__(256) void gvec_head_kernel(int t0,
    const u16* __restrict__ node, const int* __restrict__ n2g,
    float* __restrict__ gv,
    const int* __restrict__ tstep, const int* __restrict__ txid,
    const int* __restrict__ astep, const int* __restrict__ axid,
    const int* __restrict__ bstep, const int* __restrict__ bzid,
    u16* __restrict__ tv, u16* __restrict__ av, u16* __restrict__ bv,
    u16* __restrict__ wbin)
{
  int b = blockIdx.x;
  if (b < 1876) {
    int tl = (b >= 938) ? 1 : 0;
    int r0 = (b - tl * 938) * 32;
    if (r0 >= NN) return;
    int h = threadIdx.x;
    const u16* nd = node + (long)tl * NN * 256;
    float* gb = gv + (long)(t0 + tl) * BATCH * 256;
    int rend = r0 + 32; if (rend > NN) rend = NN;
    int gprev = n2g[r0];
    float acc = 0.f;
    for (int r = r0; r < rend; r++) {
      int g = n2g[r];
      if (g != gprev) { atomicAdd(gb + gprev * 256 + h, acc); acc = 0.f; gprev = g; }
      acc += b2f(nd[(long)r * 256 + h]);
    }
    atomicAdd(gb + gprev * 256 + h, acc);
    return;
  }
  int wave = threadIdx.x >> 6, lane = threadIdx.x & 63;
  int r = (b - 1876) * 4 + wave;
  int c = lane * 4;
  if (r < PT) {
    int st = tstep[r];
    if (st < t0 || st >= t0 + 2) return;
    ushort4 v = *(const ushort4*)(node + ((long)(st - t0) * NN + txid[r]) * 256 + c);
    *(ushort4*)(tv + (long)r * 544 + 256 + c) = v;
  } else if (r < PT + PA) {
    int i = r - PT;
    int st = astep[i];
    if (st < t0 || st >= t0 + 2) return;
    ushort4 v = *(const ushort4*)(node + ((long)(st - t0) * NN + axid[i]) * 256 + c);
    *(ushort4*)(av + (long)i * 544 + 256 + c) = v;
  } else if (r < PALL) {
    int i = r - PT - PA;
    int st = bstep[i];
    if (st < t0 || st >= t0 + 2) return;
    ushort4 v = *(const ushort4*)(node + ((long)(st - t0) * NN + bzid[i]) * 256 + c);
    *(ushort4*)(bv + (long)i * 800 + 512 + c) = v;
    *(ushort4*)(wbin + (long)i * 288 + c) = v;
  }
}

// fill gvec / src / one-hot segments of head inputs (after all steps)
__global__ __launch_bounds__(256) void build_static_kernel(
    const float* __restrict__ gvec, const float* __restrict__ src,
    const int* __restrict__ tstep, const int* __restrict__ tbid,
    const int* __restrict__ astep, const int* __restrict__ abid,
    const int* __restrict__ bstep, const int* __restrict__ bbid,
    const int* __restrict__ blabel, const int* __restrict__ batype,
    u16* __restrict__ tv, u16* __restrict__ av, u16* __restrict__ bv,
    u16* __restrict__ wbin, u16* __restrict__ rbin)
{
  int wave = threadIdx.x >> 6, lane = threadIdx.x & 63;
  int r = blockIdx.x * 4 + wave;
  int c = lane * 4;
  if (r < PT) {
    int st = tstep[r], bid = tbid[r];
    const float* g = gvec + ((long)st * BATCH + bid) * 256;
    u16* d = tv + (long)r * 544;
    float4 g4 = *(const float4*)(g + c);
    d[c] = f2b(g4.x); d[c + 1] = f2b(g4.y); d[c + 2] = f2b(g4.z); d[c + 3] = f2b(g4.w);
    if (lane < 8) {
      float4 s4 = *(const float4*)(src + bid * 32 + c);
      d[512 + c] = f2b(s4.x); d[512 + c + 1] = f2b(s4.y);
      d[512 + c + 2] = f2b(s4.z); d[512 + c + 3] = f2b(s4.w);
    }
  } else if (r < PT + PA) {
    int i = r - PT;
    int st = astep[i], bid = abid[i];
    const float* g = gvec + ((long)st * BATCH + bid) * 256;
    u16* d = av + (long)i * 544;
    float4 g4 = *(const float4*)(g + c);
    d[c] = f2b(g4.x); d[c + 1] = f2b(g4.y); d[c + 2] = f2b(g4.z); d[c + 3] = f2b(g4.w);
    if (lane < 8) {
      float4 s4 = *(const float4*)(src + bid * 32 + c);
      d[512 + c] = f2b(s4.x); d[512 + c + 1] = f2b(s4.y);
      d[512 + c + 2] = f2b(s4.z); d[512 + c + 3] = f2b(s4.w);
    }
  } else if (r < PALL) {
    int i = r - PT - PA;
    int st = bstep[i], bid = bbid[i];
    const float* g = gvec + ((long)st * BATCH + bid) * 256;
    u16* d = bv + (long)i * 800;
    float4 g4 = *(const float4*)(g + c);
    d[c] = f2b(g4.x); d[c + 1] = f2b(g4.y); d[c + 2] = f2b(g4.z); d[c + 3] = f2b(g4.w);
    if (lane < 8) {
      float4 s4 = *(const float4*)(src + bid * 32 + c);
      d[768 + c] = f2b(s4.x); d[768 + c + 1] = f2b(s4.y);
      d[768 + c + 2] = f2b(s4.z); d[768 + c + 3] = f2b(s4.w);
      int bl = blabel[i];
      u16* wd = wbin + (long)i * 288 + 256;
      for (int q = 0; q < 4; q++) {
        int k = c + q;
        wd[k] = f2b((k < NBOND && bl == k) ? 1.f : 0.f);
      }
    }
    if (lane < 16) {
      int at = batype[i];
      u16* rd = rbin + (long)i * 320 + 256;
      for (int q = 0; q < 4; q++) {
        int k = c + q;
        rd[k] = f2b((k < VV && at == k) ? 1.f : 0.f);
      }
    }
  }
}

// rbin[r][0:256] = sum_{j in [gs[r], r)} wb[j] * (blabel[j] > 0)
__global__ __launch_bounds__(256) void hist_kernel(
    const u16* __restrict__ wb, const int* __restrict__ gs_arr,
    const int* __restrict__ blabel, u16* __restrict__ rbin)
{
  int wave = threadIdx.x >> 6, lane = threadIdx.x & 63;
  int r = blockIdx.x * 4 + wave;
  if (r >= PB) return;
  int c = lane * 4;
  float a0 = 0.f, a1 = 0.f, a2 = 0.f, a3 = 0.f;
  int gs = gs_arr[r];
  for (int j = gs; j < r; j++) {
    if (blabel[j] > 0) {
      ushort4 g = *(const ushort4*)(wb + (long)j * 256 + c);
      a0 += b2f(g.x); a1 += b2f(g.y); a2 += b2f(g.z); a3 += b2f(g.w);
    }
  }
  u16* rd = rbin + (long)r * 320;
  rd[c] = f2b(a0); rd[c + 1] = f2b(a1); rd[c + 2] = f2b(a2); rd[c + 3] = f2b(a3);
}

// ---------------------------------------------------------------------------
extern "C" void kernel_launch(void* const* d_in, const int* in_sizes, int n_in,
                              void* d_out, int out_size, void* d_ws, size_t ws_size,
                              hipStream_t stream)
{
  const float* src      = (const float*)d_in[0];
  const float* fnode    = (const float*)d_in[1];
  const float* fmess    = (const float*)d_in[2];
  const float* W_h      = (const float*)d_in[3];
  const float* U_h      = (const float*)d_in[4];
  const float* b_h      = (const float*)d_in[5];
  const float* W_o      = (const float*)d_in[6];
  const float* b_o      = (const float*)d_in[7];
  const float* topo_w1  = (const float*)d_in[8];
  const float* topo_b1  = (const float*)d_in[9];
  const float* topo_w2  = (const float*)d_in[10];
  const float* topo_b2  = (const float*)d_in[11];
  const float* atom_w1  = (const float*)d_in[12];
  const float* atom_b1  = (const float*)d_in[13];
  const float* atom_w2  = (const float*)d_in[14];
  const float* atom_b2  = (const float*)d_in[15];
  const float* bond_w1  = (const float*)d_in[16];
  const float* bond_b1  = (const float*)d_in[17];
  const float* bond_w2  = (const float*)d_in[18];
  const float* bond_b2  = (const float*)d_in[19];
  const float* rbond_w  = (const float*)d_in[20];
  const float* rbond_b  = (const float*)d_in[21];
  const float* wbond_w  = (const float*)d_in[22];
  const float* wbond_b  = (const float*)d_in[23];
  const int* agraph     = (const int*)d_in[24];
  const int* bgraph     = (const int*)d_in[25];
  const int* node2graph = (const int*)d_in[26];
  const int* emask      = (const int*)d_in[27];
  const int* vmask      = (const int*)d_in[28];
  const int* topo_step  = (const int*)d_in[29];
  const int* topo_bid   = (const int*)d_in[30];
  const int* topo_xid   = (const int*)d_in[31];
  const int* topo_label = (const int*)d_in[32];
  const int* atom_step  = (const int*)d_in[33];
  const int* atom_bid   = (const int*)d_in[34];
  const int* atom_xid   = (const int*)d_in[35];
  const int* atom_label = (const int*)d_in[36];
  const int* bond_step  = (const int*)d_in[37];
  const int* bond_bid   = (const int*)d_in[38];
  const int* bond_zid   = (const int*)d_in[39];
  const int* bond_atype = (const int*)d_in[40];
  const int* bond_label = (const int*)d_in[41];
  const int* bond_gs    = (const int*)d_in[42];

  char* wp = (char*)d_ws;
  auto alloc = [&](size_t bytes) -> char* {
    char* p = wp; wp += (bytes + 255) & ~(size_t)255; return p;
  };
  // ~128 MB total -> loop working set comfortably L3-resident
  u8*  preB    = (u8*)alloc((size_t)NE * 256);            // fp8, 15.4 MB
  u8*  hu1B    = (u8*)alloc((size_t)NE * 256);            // fp8, 15.4 MB
  u16* foB     = (u16*)alloc((size_t)NN * 256 * 2);       // bf16
  float* gvec  = (float*)alloc((size_t)TT * BATCH * 256 * 4);
  u16* Wh_t    = (u16*)alloc(256 * 256 * 2);
  u16* Uh_t    = (u16*)alloc(256 * 256 * 2);
  u16* Wo1_t   = (u16*)alloc(256 * 256 * 2);
  u16* Wo2_t   = (u16*)alloc(256 * 256 * 2);
  u16* tw1_t   = (u16*)alloc(256 * 544 * 2);
  u16* aw1_t   = (u16*)alloc(256 * 544 * 2);
  u16* bw1_t   = (u16*)alloc(256 * 800 * 2);
  u16* rw_t    = (u16*)alloc(256 * 320 * 2);
  u16* ww_t    = (u16*)alloc(256 * 288 * 2);
  u16* w2c     = (u16*)alloc(3 * 64 * 256 * 2);
  float* b2c   = (float*)alloc(192 * 4);
  u16* tva     = (u16*)alloc((size_t)(PT + PA) * 544 * 2);
  u16* bv      = (u16*)alloc((size_t)PB * 800 * 2);
  u16* wbin    = (u16*)alloc((size_t)PB * 288 * 2);
  u16* rbin    = (u16*)alloc((size_t)PB * 320 * 2);
  u16* wb      = (u16*)alloc((size_t)PB * 256 * 2);
  u16* hid_all = (u16*)alloc((size_t)PALL * 256 * 2);
  float* logitsL = (float*)alloc((size_t)PALL * 64 * 4);
  u8*  G       = (u8*)alloc((size_t)2 * NE * 256);        // fp8, 30.7 MB
  u8*  T       = (u8*)alloc((size_t)2 * NE * 256);        // fp8, 30.7 MB
  u16* nodeB   = (u16*)alloc((size_t)2 * NN * 256 * 2);   // bf16, 30.7 MB
  u16* tv      = tva;
  u16* av      = tva + (size_t)PT * 544;

  float* out = (float*)d_out;

  init_zero_kernel<<<1536, 256, 0, stream>>>(gvec, out);
  transpose_all_kernel<<<3520, 256, 0, stream>>>(W_h, U_h, W_o, topo_w1, atom_w1, bond_w1,
      rbond_w, wbond_w, Wh_t, Uh_t, Wo1_t, Wo2_t, tw1_t, aw1_t, bw1_t, rw_t, ww_t);
  build_w2c_kernel<<<192, 256, 0, stream>>>(topo_w2, topo_b2, atom_w2, atom_b2,
                                            bond_w2, bond_b2, w2c, b2c);

  // step-invariant precomputes
  gemm_n256_kernel<1, 1><<<(NE + 127) / 128, 512, 0, stream>>>(
      fmess, NE, Wh_t, preB, nullptr);                         // pre = fmess@W_h  (fp8)
  gemm_n256_kernel<1, 0><<<(NN + 127) / 128, 512, 0, stream>>>(
      fnode, NN, Wo1_t, foB, nullptr);                         // fo = fnode@Wo1  (bf16)
  gemm_n256_kernel<2, 1><<<(NE + 127) / 128, 512, 0, stream>>>(
      preB, NE, Uh_t, hu1B, b_h);                              // hu1 = h1@U_h    (fp8)

  for (int t0 = 0; t0 < TT; t0 += 2) {
    int M2 = 2 * NE;
    int gb = 2 * NE / 8;
    int mb = (M2 + 127) / 128;
    gather_e2_kernel<1><<<gb, 256, 0, stream>>>(hu1B, preB, bgraph, emask, b_h, t0, G);
    gemm_n256_kernel<3, 1><<<mb, 512, 0, stream>>>(G, M2, Uh_t, T, nullptr);
    gather_e2_kernel<0><<<gb, 256, 0, stream>>>(T, preB, bgraph, emask, b_h, t0, G);
    gemm_n256_kernel<3, 1><<<mb, 512, 0, stream>>>(G, M2, Uh_t, T, nullptr);
    gather_e2_kernel<0><<<gb, 256, 0, stream>>>(T, preB, bgraph, emask, b_h, t0, G);
    gemm_n256_kernel<3, 1><<<mb, 512, 0, stream>>>(G, M2, Wo2_t, T, nullptr);
    gather_n2_kernel<<<2 * NN / 8, 256, 0, stream>>>(T, foB, agraph, emask, b_o,
                                                     vmask, t0, nodeB);
    gvec_head_kernel<<<3220, 256, 0, stream>>>(t0, nodeB, node2graph, gvec,
        topo_step, topo_xid, atom_step, atom_xid, bond_step, bond_zid,
        tv, av, bv, wbin);
  }

  // static head-input segments
  build_static_kernel<<<1344, 256, 0, stream>>>(gvec, src,
      topo_step, topo_bid, atom_step, atom_bid, bond_step, bond_bid,
      bond_label, bond_atype, tv, av, bv, wbin, rbin);

  // heads -> hid_all
  gemm_ta_kernel<<<dim3((PT + PA) / 128, 2), 256, 0, stream>>>(tva, tw1_t, aw1_t,
                                                               topo_b1, atom_b1, hid_all);
  gemm_bt_kernel<1><<<dim3(20, 2), 256, 0, stream>>>(wbin, 288, PB, ww_t, 288,
                                                     wb, 256, wbond_b);
  hist_kernel<<<640, 256, 0, stream>>>(wb, bond_gs, bond_label, rbin);
  gemm_bt_kernel<1><<<dim3(20, 2), 256, 0, stream>>>(rbin, 320, PB, rw_t, 320,
                                                     bv + 256, 800, rbond_b);
  gemm_bt_kernel<1><<<dim3(20, 2), 256, 0, stream>>>(bv, 800, PB, bw1_t, 800,
                                                     hid_all + (size_t)(PT + PA) * 256,
                                                     256, bond_b1);

  // losses: logits GEMM + finalize
  gemm_logits_kernel<<<PALL / 128, 256, 0, stream>>>(hid_all, w2c, b2c, logitsL);
  loss_finalize_kernel<<<PALL / 4, 256, 0, stream>>>(logitsL, topo_label, atom_label,
                                                     bond_label, out);
}